// Round 1
// 181.445 us; speedup vs baseline: 1.0428x; 1.0428x over previous
//
#include <hip/hip_runtime.h>
#include <hip/hip_fp16.h>
#include <cmath>

#define NN 50000
#define NE 800000
#define SLOPE 0.2f
#define NTILES 782           // ceil(50000/64)
#define DSTRIDE 64           // fixed CSR slots per node (max expected degree ~36)
#define ESTRIDE (NTILES * 256)

// workspace layout (4-byte units) — total ~29 MB
#define OFF_H    0           // __half h[NN*128]:    3,200,000 dwords
#define OFF_H8   3200000     // fp8 h8[NN*128]:      1,600,000 dwords
#define OFF_AL   4800000     // float al[NN*8]:        400,000
#define OFF_AR   5200000     // float ar[NN*8]:        400,000
#define OFF_CUR  5600000     // int cur[NN]:            50,000 (zeroed inside project)
#define OFF_CSR  5650000     // ushort csr[NN*64]:   1,600,000 dwords

using half8   = __attribute__((ext_vector_type(8))) _Float16;
using floatx4 = __attribute__((ext_vector_type(4))) float;
using floatx2 = __attribute__((ext_vector_type(2))) float;
using intx4   = __attribute__((ext_vector_type(4))) int;

#define WST 136

// MFMA projection: h = fp16(X @ W^T + b), h8 = fp8(same); al/ar = attention dots.
// Also zeroes cur[] (kernel boundary orders it before scatter's atomics).
__global__ __launch_bounds__(256) void project_kernel(
    const float* __restrict__ X,    // [NN,128]
    const float* __restrict__ W,    // [128,128] row-major W[o][k]
    const float* __restrict__ Bv,   // [128]
    const float* __restrict__ Av,   // [32]
    __half* __restrict__ h, unsigned char* __restrict__ h8,
    float* __restrict__ al, float* __restrict__ ar,
    int* __restrict__ cur)
{
    __shared__ _Float16 Wh[128 * WST];   // 34.8 KB
    __shared__ _Float16 Cs[64 * WST];    // 17.4 KB
    __shared__ float As[32];
    const int tid = threadIdx.x;
    const int bid = blockIdx.x;

    // zero degree counters (replaces the memset dispatch)
    for (int i = bid * 256 + tid; i < NN; i += ESTRIDE) cur[i] = 0;

    for (int i = tid; i < 128 * 128; i += 256) {
        int o = i >> 7, k = i & 127;
        Wh[o * WST + k] = (_Float16)W[i];
    }
    if (tid < 32) As[tid] = Av[tid];
    __syncthreads();

    const int wave = tid >> 6;
    const int lane = tid & 63;
    const int q = lane >> 4;
    const int n = lane & 15;
    const int gn = bid * 64 + wave * 16 + n;
    const bool valid = gn < NN;
    const float* xrow = X + ((long)gn << 7);

    half8 afrag[4];
#pragma unroll
    for (int kc = 0; kc < 4; ++kc) {
        float4 x0 = make_float4(0.f, 0.f, 0.f, 0.f), x1 = x0;
        if (valid) {
            x0 = *(const float4*)(xrow + kc * 32 + q * 8);
            x1 = *(const float4*)(xrow + kc * 32 + q * 8 + 4);
        }
        half8 a;
        a[0] = (_Float16)x0.x; a[1] = (_Float16)x0.y;
        a[2] = (_Float16)x0.z; a[3] = (_Float16)x0.w;
        a[4] = (_Float16)x1.x; a[5] = (_Float16)x1.y;
        a[6] = (_Float16)x1.z; a[7] = (_Float16)x1.w;
        afrag[kc] = a;
    }

    floatx4 acc[8];
#pragma unroll
    for (int nt = 0; nt < 8; ++nt) {
        float b = Bv[nt * 16 + n];
        acc[nt][0] = b; acc[nt][1] = b; acc[nt][2] = b; acc[nt][3] = b;
    }
#pragma unroll
    for (int nt = 0; nt < 8; ++nt) {
        const _Float16* wrow = &Wh[(nt * 16 + n) * WST];
#pragma unroll
        for (int kc = 0; kc < 4; ++kc) {
            half8 bfrag = *(const half8*)(wrow + kc * 32 + q * 8);
            acc[nt] = __builtin_amdgcn_mfma_f32_16x16x32_f16(afrag[kc], bfrag, acc[nt], 0, 0, 0);
        }
    }

    // C/D layout: lane holds C[m=q*4+r][n] -> Cs[node][feature]
    _Float16* cw = &Cs[(wave * 16) * WST];
#pragma unroll
    for (int nt = 0; nt < 8; ++nt) {
#pragma unroll
        for (int r = 0; r < 4; ++r) {
            cw[(q * 4 + r) * WST + nt * 16 + n] = (_Float16)acc[nt][r];
        }
    }
    __syncthreads();

    {   // h (fp16) + h8 (fp8): thread -> (node row = tid>>2, 32-feature chunk = tid&3)
        int rw = tid >> 2, ch = tid & 3;
        int gnode = bid * 64 + rw;
        if (gnode < NN) {
            const uint4* src = (const uint4*)&Cs[rw * WST + ch * 32];
            uint4 v[4] = { src[0], src[1], src[2], src[3] };
            uint4* dst = (uint4*)&h[((long)gnode << 7) + ch * 32];
            dst[0] = v[0]; dst[1] = v[1]; dst[2] = v[2]; dst[3] = v[3];

            const unsigned int* dw = (const unsigned int*)v;
            unsigned int res[8];
#pragma unroll
            for (int w = 0; w < 8; ++w) {
                unsigned int lo = dw[2 * w], hi = dw[2 * w + 1];
                float2 f0 = __half22float2(*(const __half2*)&lo);
                float2 f1 = __half22float2(*(const __half2*)&hi);
                unsigned int r = 0;
                r = __builtin_amdgcn_cvt_pk_fp8_f32(f0.x, f0.y, r, false);
                r = __builtin_amdgcn_cvt_pk_fp8_f32(f1.x, f1.y, r, true);
                res[w] = r;
            }
            uint4* d8 = (uint4*)&h8[((long)gnode << 7) + ch * 32];
            d8[0] = make_uint4(res[0], res[1], res[2], res[3]);
            d8[1] = make_uint4(res[4], res[5], res[6], res[7]);
        }
    }
    for (int p = tid; p < 512; p += 256) {   // al/ar: 64 nodes x 8 heads
        int nd = p >> 3, hh = p & 7;
        int gnode = bid * 64 + nd;
        if (gnode >= NN) continue;
        const _Float16* c = &Cs[nd * WST + hh * 16];
        float pL = 0.f, pR = 0.f;
#pragma unroll
        for (int f = 0; f < 16; ++f) {
            float hv = (float)c[f];
            pL = fmaf(hv, As[f], pL);
            pR = fmaf(hv, As[16 + f], pR);
        }
        al[gnode * 8 + hh] = pL;
        ar[gnode * 8 + hh] = pR;
    }
}

// ---------------------------------------------------------------------------
// scatter v2: tgt-range x XCD-partitioned CSR build.
//
// Old version: 800K threads, each doing one random 2B csr store -> every store
// dirtied a random 64B line from a random XCD; 8 non-coherent L2s never
// coalesced them -> WRITE_SIZE 44.4 MB (~25x amplification) at ~0.9 TB/s
// random-write throughput = the whole 50 us.
//
// New version: grid = 8 groups x 196 chunks. Block b: group r = b&7 (lands on
// XCD r under round-robin dispatch -- perf heuristic ONLY), chunk = b>>3
// (4096 edges). Each block scans its chunk with nontemporal int4 loads and
// commits only edges with tgt in [r*6250, (r+1)*6250). Every edge is committed
// by exactly one block regardless of the blockIdx->XCD mapping (correctness is
// mapping-independent). All stores to a given csr/cur line now issue from one
// group -> one L2 -> ~16 slot-stores coalesce per line before writeback.
// Cost: ei re-read 8x (51 MB) -- streaming, Infinity-Cache-resident (6.4 MB
// array), a few us. Nontemporal loads keep the streaming ei traffic from
// evicting the csr lines whose L2 residency is the entire point.
// ---------------------------------------------------------------------------
#define SC_CHUNK  4096                          // edges per chunk (256 thr x 4 iter x int4)
#define SC_NCHUNK ((NE + SC_CHUNK - 1) / SC_CHUNK)   // 196
#define SC_RANGE  (NN / 8)                      // 6250 tgt nodes per group

__global__ __launch_bounds__(256) void scatter_kernel(
    const int* __restrict__ ei,
    int* __restrict__ cur, unsigned short* __restrict__ csr)
{
    const int grp   = blockIdx.x & 7;
    const int chunk = blockIdx.x >> 3;
    const int lo    = grp * SC_RANGE;
    const int ebase = chunk * SC_CHUNK + threadIdx.x * 4;
#pragma unroll
    for (int it = 0; it < 4; ++it) {
        const int e0 = ebase + it * 1024;       // NE % 4 == 0, e0 % 4 == 0 -> int4 safe when e0 < NE
        if (e0 >= NE) break;
        intx4 tg = __builtin_nontemporal_load((const intx4*)(ei + NE + e0));
        intx4 sr = __builtin_nontemporal_load((const intx4*)(ei + e0));
#pragma unroll
        for (int k = 0; k < 4; ++k) {
            const int tgt = tg[k];
            if ((unsigned)(tgt - lo) < (unsigned)SC_RANGE) {
                int slot = atomicAdd(&cur[tgt], 1);
                if (slot < DSTRIDE) csr[(tgt << 6) + slot] = (unsigned short)sr[k];
            }
        }
    }
}

// one wave per node; 8-edge chunks. Lane (hh=lane>>3, el=lane&7) computes ONE
// exp for (edge el, head hh), shares via per-wave LDS slab (4x ds_read_b128
// per chunk, not bpermute chains); then all 8 h8 loads issue back-to-back.
__global__ __launch_bounds__(256) void gather_kernel(
    const int* __restrict__ cur, const unsigned short* __restrict__ csr,
    const float* __restrict__ al, const float* __restrict__ ar,
    const __half* __restrict__ h, const unsigned char* __restrict__ h8,
    float* __restrict__ out)
{
    __shared__ __align__(16) float se[4][64];
    __shared__ __align__(16) int ssrc[4][8];
    const int wid = threadIdx.x >> 6;
    const int n = blockIdx.x * 4 + wid;
    if (n >= NN) return;
    const int lane = threadIdx.x & 63;
    const int c2 = lane << 1;
    const int hh = lane >> 3;
    const int el = lane & 7;
    const int deg = cur[n];                 // true degree (skip term)
    const int degc = min(deg, DSTRIDE);     // iterated edges
    const long base = (long)n << 6;
    const float aLt = al[n * 8 + hh];

    float acc0 = 0.0f, acc1 = 0.0f, den = 0.0f;
    int j = 0;
    for (; j + 7 < degc; j += 8) {
        int msrc = (int)csr[base + j + el];
        float v = aLt + ar[msrc * 8 + hh];
        v = v > 0.0f ? v : SLOPE * v;
        float me = __expf(fminf(v, 60.0f));
        se[wid][lane] = me;                 // lane = hh*8+el
        if (hh == 0) ssrc[wid][el] = msrc;
        // per-wave LDS reuse: DS ops are in-order within a wave; fence stops
        // compiler reordering. NO __syncthreads (waves have divergent trips).
        __asm__ __volatile__("s_waitcnt lgkmcnt(0)" ::: "memory");
        float4 e03 = *(const float4*)&se[wid][hh << 3];
        float4 e47 = *(const float4*)&se[wid][(hh << 3) + 4];
        int4 s03 = *(const int4*)&ssrc[wid][0];
        int4 s47 = *(const int4*)&ssrc[wid][4];
        unsigned short u0 = *(const unsigned short*)&h8[((long)s03.x << 7) + c2];
        unsigned short u1 = *(const unsigned short*)&h8[((long)s03.y << 7) + c2];
        unsigned short u2 = *(const unsigned short*)&h8[((long)s03.z << 7) + c2];
        unsigned short u3 = *(const unsigned short*)&h8[((long)s03.w << 7) + c2];
        unsigned short u4 = *(const unsigned short*)&h8[((long)s47.x << 7) + c2];
        unsigned short u5 = *(const unsigned short*)&h8[((long)s47.y << 7) + c2];
        unsigned short u6 = *(const unsigned short*)&h8[((long)s47.z << 7) + c2];
        unsigned short u7 = *(const unsigned short*)&h8[((long)s47.w << 7) + c2];
        floatx2 g0 = __builtin_amdgcn_cvt_pk_f32_fp8(u0, false);
        floatx2 g1 = __builtin_amdgcn_cvt_pk_f32_fp8(u1, false);
        floatx2 g2 = __builtin_amdgcn_cvt_pk_f32_fp8(u2, false);
        floatx2 g3 = __builtin_amdgcn_cvt_pk_f32_fp8(u3, false);
        floatx2 g4 = __builtin_amdgcn_cvt_pk_f32_fp8(u4, false);
        floatx2 g5 = __builtin_amdgcn_cvt_pk_f32_fp8(u5, false);
        floatx2 g6 = __builtin_amdgcn_cvt_pk_f32_fp8(u6, false);
        floatx2 g7 = __builtin_amdgcn_cvt_pk_f32_fp8(u7, false);
        den += (e03.x + e03.y) + (e03.z + e03.w) + (e47.x + e47.y) + (e47.z + e47.w);
        acc0 = fmaf(e03.x, g0[0], fmaf(e03.y, g1[0], fmaf(e03.z, g2[0], fmaf(e03.w, g3[0], acc0))));
        acc1 = fmaf(e03.x, g0[1], fmaf(e03.y, g1[1], fmaf(e03.z, g2[1], fmaf(e03.w, g3[1], acc1))));
        acc0 = fmaf(e47.x, g4[0], fmaf(e47.y, g5[0], fmaf(e47.z, g6[0], fmaf(e47.w, g7[0], acc0))));
        acc1 = fmaf(e47.x, g4[1], fmaf(e47.y, g5[1], fmaf(e47.z, g6[1], fmaf(e47.w, g7[1], acc1))));
    }
    for (; j < degc; ++j) {   // tail: scalar path
        int s0 = (int)csr[base + j];
        float v0 = aLt + ar[s0 * 8 + hh];
        v0 = v0 > 0.0f ? v0 : SLOPE * v0;
        float e0 = __expf(fminf(v0, 60.0f));
        unsigned short u0 = *(const unsigned short*)&h8[((long)s0 << 7) + c2];
        floatx2 g0 = __builtin_amdgcn_cvt_pk_f32_fp8(u0, false);
        den += e0;
        acc0 = fmaf(e0, g0[0], acc0);
        acc1 = fmaf(e0, g0[1], acc1);
    }

    float2 hs = __half22float2(*(const __half2*)&h[((long)n << 7) + c2]);
    float degf = (float)deg;
    float inv = (den > 0.0f) ? 1.0f / den : 0.0f;
    float o0 = fmaf(degf, hs.x, acc0 * inv);
    float o1 = fmaf(degf, hs.y, acc1 * inv);
    o0 = o0 > 0.0f ? o0 : expm1f(o0);
    o1 = o1 > 0.0f ? o1 : expm1f(o1);
    *(float2*)&out[((long)n << 7) + c2] = make_float2(o0, o1);
}

extern "C" void kernel_launch(void* const* d_in, const int* in_sizes, int n_in,
                              void* d_out, int out_size, void* d_ws, size_t ws_size,
                              hipStream_t stream) {
    const float* X = (const float*)d_in[0];
    const int* ei  = (const int*)d_in[1];
    const float* W = (const float*)d_in[2];
    const float* B = (const float*)d_in[3];
    const float* A = (const float*)d_in[4];
    float* ws  = (float*)d_ws;
    __half* h  = (__half*)(ws + OFF_H);
    unsigned char* h8 = (unsigned char*)(ws + OFF_H8);
    float* al  = ws + OFF_AL;
    float* ar  = ws + OFF_AR;
    int* cur   = (int*)ws + OFF_CUR;
    unsigned short* csr = (unsigned short*)(ws + OFF_CSR);
    float* out = (float*)d_out;

    project_kernel<<<NTILES, 256, 0, stream>>>(X, W, B, A, h, h8, al, ar, cur);
    scatter_kernel<<<8 * SC_NCHUNK, 256, 0, stream>>>(ei, cur, csr);
    gather_kernel<<<(NN + 3) / 4, 256, 0, stream>>>(cur, csr, al, ar, h, h8, out);
}

// Round 5
// 177.993 us; speedup vs baseline: 1.0631x; 1.0194x over previous
//
#include <hip/hip_runtime.h>
#include <hip/hip_fp16.h>
#include <cmath>

#define NN 50000
#define NE 800000
#define SLOPE 0.2f
#define NTILES 782           // ceil(50000/64)
#define DSTRIDE 64           // fixed CSR slots per node (max expected degree ~36)
#define ESTRIDE (NTILES * 256)

// workspace layout (4-byte units) — total ~29 MB
#define OFF_H    0           // __half h[NN*128]:    3,200,000 dwords
#define OFF_H8   3200000     // fp8 h8[NN*128]:      1,600,000 dwords
#define OFF_AL   4800000     // float al[NN*8]:        400,000
#define OFF_AR   5200000     // float ar[NN*8]:        400,000
#define OFF_CUR  5600000     // int cur[NN]:            50,000 (zeroed inside project)
#define OFF_CSR  5650000     // ushort csr[NN*64]:   1,600,000 dwords

using half8   = __attribute__((ext_vector_type(8))) _Float16;
using floatx4 = __attribute__((ext_vector_type(4))) float;
using floatx2 = __attribute__((ext_vector_type(2))) float;
using intx4   = __attribute__((ext_vector_type(4))) int;

#define WST 136

// MFMA projection: h = fp16(X @ W^T + b), h8 = fp8(same); al/ar = attention dots.
// Also zeroes cur[] (kernel boundary orders it before scatter's atomics).
__global__ __launch_bounds__(256) void project_kernel(
    const float* __restrict__ X,    // [NN,128]
    const float* __restrict__ W,    // [128,128] row-major W[o][k]
    const float* __restrict__ Bv,   // [128]
    const float* __restrict__ Av,   // [32]
    __half* __restrict__ h, unsigned char* __restrict__ h8,
    float* __restrict__ al, float* __restrict__ ar,
    int* __restrict__ cur)
{
    __shared__ _Float16 Wh[128 * WST];   // 34.8 KB
    __shared__ _Float16 Cs[64 * WST];    // 17.4 KB
    __shared__ float As[32];
    const int tid = threadIdx.x;
    const int bid = blockIdx.x;

    // zero degree counters (replaces the memset dispatch)
    for (int i = bid * 256 + tid; i < NN; i += ESTRIDE) cur[i] = 0;

    for (int i = tid; i < 128 * 128; i += 256) {
        int o = i >> 7, k = i & 127;
        Wh[o * WST + k] = (_Float16)W[i];
    }
    if (tid < 32) As[tid] = Av[tid];
    __syncthreads();

    const int wave = tid >> 6;
    const int lane = tid & 63;
    const int q = lane >> 4;
    const int n = lane & 15;
    const int gn = bid * 64 + wave * 16 + n;
    const bool valid = gn < NN;
    const float* xrow = X + ((long)gn << 7);

    half8 afrag[4];
#pragma unroll
    for (int kc = 0; kc < 4; ++kc) {
        float4 x0 = make_float4(0.f, 0.f, 0.f, 0.f), x1 = x0;
        if (valid) {
            x0 = *(const float4*)(xrow + kc * 32 + q * 8);
            x1 = *(const float4*)(xrow + kc * 32 + q * 8 + 4);
        }
        half8 a;
        a[0] = (_Float16)x0.x; a[1] = (_Float16)x0.y;
        a[2] = (_Float16)x0.z; a[3] = (_Float16)x0.w;
        a[4] = (_Float16)x1.x; a[5] = (_Float16)x1.y;
        a[6] = (_Float16)x1.z; a[7] = (_Float16)x1.w;
        afrag[kc] = a;
    }

    floatx4 acc[8];
#pragma unroll
    for (int nt = 0; nt < 8; ++nt) {
        float b = Bv[nt * 16 + n];
        acc[nt][0] = b; acc[nt][1] = b; acc[nt][2] = b; acc[nt][3] = b;
    }
#pragma unroll
    for (int nt = 0; nt < 8; ++nt) {
        const _Float16* wrow = &Wh[(nt * 16 + n) * WST];
#pragma unroll
        for (int kc = 0; kc < 4; ++kc) {
            half8 bfrag = *(const half8*)(wrow + kc * 32 + q * 8);
            acc[nt] = __builtin_amdgcn_mfma_f32_16x16x32_f16(afrag[kc], bfrag, acc[nt], 0, 0, 0);
        }
    }

    // C/D layout: lane holds C[m=q*4+r][n] -> Cs[node][feature]
    _Float16* cw = &Cs[(wave * 16) * WST];
#pragma unroll
    for (int nt = 0; nt < 8; ++nt) {
#pragma unroll
        for (int r = 0; r < 4; ++r) {
            cw[(q * 4 + r) * WST + nt * 16 + n] = (_Float16)acc[nt][r];
        }
    }
    __syncthreads();

    {   // h (fp16) + h8 (fp8): thread -> (node row = tid>>2, 32-feature chunk = tid&3)
        int rw = tid >> 2, ch = tid & 3;
        int gnode = bid * 64 + rw;
        if (gnode < NN) {
            const uint4* src = (const uint4*)&Cs[rw * WST + ch * 32];
            uint4 v[4] = { src[0], src[1], src[2], src[3] };
            uint4* dst = (uint4*)&h[((long)gnode << 7) + ch * 32];
            dst[0] = v[0]; dst[1] = v[1]; dst[2] = v[2]; dst[3] = v[3];

            const unsigned int* dw = (const unsigned int*)v;
            unsigned int res[8];
#pragma unroll
            for (int w = 0; w < 8; ++w) {
                unsigned int lo = dw[2 * w], hi = dw[2 * w + 1];
                float2 f0 = __half22float2(*(const __half2*)&lo);
                float2 f1 = __half22float2(*(const __half2*)&hi);
                unsigned int r = 0;
                r = __builtin_amdgcn_cvt_pk_fp8_f32(f0.x, f0.y, r, false);
                r = __builtin_amdgcn_cvt_pk_fp8_f32(f1.x, f1.y, r, true);
                res[w] = r;
            }
            uint4* d8 = (uint4*)&h8[((long)gnode << 7) + ch * 32];
            d8[0] = make_uint4(res[0], res[1], res[2], res[3]);
            d8[1] = make_uint4(res[4], res[5], res[6], res[7]);
        }
    }
    for (int p = tid; p < 512; p += 256) {   // al/ar: 64 nodes x 8 heads
        int nd = p >> 3, hh = p & 7;
        int gnode = bid * 64 + nd;
        if (gnode >= NN) continue;
        const _Float16* c = &Cs[nd * WST + hh * 16];
        float pL = 0.f, pR = 0.f;
#pragma unroll
        for (int f = 0; f < 16; ++f) {
            float hv = (float)c[f];
            pL = fmaf(hv, As[f], pL);
            pR = fmaf(hv, As[16 + f], pR);
        }
        al[gnode * 8 + hh] = pL;
        ar[gnode * 8 + hh] = pR;
    }
}

// ---------------------------------------------------------------------------
// scatter v2: tgt-range x XCD-partitioned CSR build (see round-1 notes: cut
// WRITE_SIZE 44.4 MB -> csr/cur lines coalesce within one XCD's L2).
// ---------------------------------------------------------------------------
#define SC_CHUNK  4096                          // edges per chunk (256 thr x 4 iter x int4)
#define SC_NCHUNK ((NE + SC_CHUNK - 1) / SC_CHUNK)   // 196
#define SC_RANGE  (NN / 8)                      // 6250 tgt nodes per group

__global__ __launch_bounds__(256) void scatter_kernel(
    const int* __restrict__ ei,
    int* __restrict__ cur, unsigned short* __restrict__ csr)
{
    const int grp   = blockIdx.x & 7;
    const int chunk = blockIdx.x >> 3;
    const int lo    = grp * SC_RANGE;
    const int ebase = chunk * SC_CHUNK + threadIdx.x * 4;
#pragma unroll
    for (int it = 0; it < 4; ++it) {
        const int e0 = ebase + it * 1024;       // NE % 4 == 0, e0 % 4 == 0 -> int4 safe when e0 < NE
        if (e0 >= NE) break;
        intx4 tg = __builtin_nontemporal_load((const intx4*)(ei + NE + e0));
        intx4 sr = __builtin_nontemporal_load((const intx4*)(ei + e0));
#pragma unroll
        for (int k = 0; k < 4; ++k) {
            const int tgt = tg[k];
            if ((unsigned)(tgt - lo) < (unsigned)SC_RANGE) {
                int slot = atomicAdd(&cur[tgt], 1);
                if (slot < DSTRIDE) csr[(tgt << 6) + slot] = (unsigned short)sr[k];
            }
        }
    }
}

// ---------------------------------------------------------------------------
// gather v3: 16-edge chunks (2x MLP: 16 h8 loads in flight; one LDS round-trip
// per 16 edges), 32-bit SADDR offsets for all random loads (uniform SGPR base
// + zext(u32 voffset) -> global_load_*_saddr, no per-load 64-bit adds), and
// packed fp32 accumulation (floatx2/floatx4 -> v_pk_fma_f32/v_pk_add_f32).
// se rows stride 20 floats: row starts hh*20 land on 8 distinct bank groups
// (hh*20 mod 32 = {0,20,8,28,16,4,24,12}) -> conflict-free b128 reads.
// ---------------------------------------------------------------------------
#define H8LD(s) (*(const unsigned short*)(h8 + ((((unsigned)(s)) << 7) | (unsigned)c2)))
#define ARLD(s) (*(const float*)((const char*)ar + ((((unsigned)(s)) << 5) | arof)))
#define CSRLD(o) (*(const unsigned short*)((const char*)csr + (o)))

__global__ __launch_bounds__(256) void gather_kernel(
    const int* __restrict__ cur, const unsigned short* __restrict__ csr,
    const float* __restrict__ al, const float* __restrict__ ar,
    const __half* __restrict__ h, const unsigned char* __restrict__ h8,
    float* __restrict__ out)
{
    __shared__ __align__(16) float se[4][160];    // 8 heads x stride 20
    __shared__ __align__(16) int ssrc[4][16];
    const int wid = threadIdx.x >> 6;
    const int n = blockIdx.x * 4 + wid;
    if (n >= NN) return;
    const int lane = threadIdx.x & 63;
    const int c2 = lane << 1;
    const int hh = lane >> 3;
    const int el = lane & 7;
    const int deg = cur[n];                 // true degree (skip term)
    const int degc = min(deg, DSTRIDE);     // iterated edges
    const unsigned cbase = ((unsigned)n) << 7;     // byte offset of node's csr row
    const unsigned arof = ((unsigned)hh) << 2;     // byte offset of head within ar row
    const float aLt = al[n * 8 + hh];
    float* serow = &se[wid][hh * 20];

    floatx2 acc2 = {0.f, 0.f};
    floatx4 den4 = {0.f, 0.f, 0.f, 0.f};
    float dent = 0.f;
    float acct0 = 0.f, acct1 = 0.f;
    int j = 0;
    for (; j + 15 < degc; j += 16) {
        const unsigned co = cbase + (((unsigned)(j + el)) << 1);
        int ms0 = (int)CSRLD(co);
        int ms1 = (int)CSRLD(co + 16u);
        float v0 = aLt + ARLD(ms0);
        float v1 = aLt + ARLD(ms1);
        v0 = v0 > 0.0f ? v0 : SLOPE * v0;
        v1 = v1 > 0.0f ? v1 : SLOPE * v1;
        float me0 = __expf(fminf(v0, 60.0f));
        float me1 = __expf(fminf(v1, 60.0f));
        serow[el] = me0;
        serow[8 + el] = me1;
        if (hh == 0) { ssrc[wid][el] = ms0; ssrc[wid][8 + el] = ms1; }
        // per-wave LDS reuse: DS ops are in-order within a wave; fence stops
        // compiler reordering. NO __syncthreads (waves have divergent trips).
        __asm__ __volatile__("s_waitcnt lgkmcnt(0)" ::: "memory");
        floatx4 ea = *(const floatx4*)&serow[0];
        floatx4 eb = *(const floatx4*)&serow[4];
        floatx4 ec = *(const floatx4*)&serow[8];
        floatx4 ed = *(const floatx4*)&serow[12];
        intx4 sa = *(const intx4*)&ssrc[wid][0];
        intx4 sb = *(const intx4*)&ssrc[wid][4];
        intx4 sc = *(const intx4*)&ssrc[wid][8];
        intx4 sd = *(const intx4*)&ssrc[wid][12];
        // 16 independent 2B loads, issued back-to-back (MLP)
        unsigned short u0  = H8LD(sa[0]);
        unsigned short u1  = H8LD(sa[1]);
        unsigned short u2  = H8LD(sa[2]);
        unsigned short u3  = H8LD(sa[3]);
        unsigned short u4  = H8LD(sb[0]);
        unsigned short u5  = H8LD(sb[1]);
        unsigned short u6  = H8LD(sb[2]);
        unsigned short u7  = H8LD(sb[3]);
        unsigned short u8  = H8LD(sc[0]);
        unsigned short u9  = H8LD(sc[1]);
        unsigned short u10 = H8LD(sc[2]);
        unsigned short u11 = H8LD(sc[3]);
        unsigned short u12 = H8LD(sd[0]);
        unsigned short u13 = H8LD(sd[1]);
        unsigned short u14 = H8LD(sd[2]);
        unsigned short u15 = H8LD(sd[3]);
        den4 += ea; den4 += eb; den4 += ec; den4 += ed;
        floatx2 g;
        g = __builtin_amdgcn_cvt_pk_f32_fp8(u0,  false); acc2 += g * ea[0];
        g = __builtin_amdgcn_cvt_pk_f32_fp8(u1,  false); acc2 += g * ea[1];
        g = __builtin_amdgcn_cvt_pk_f32_fp8(u2,  false); acc2 += g * ea[2];
        g = __builtin_amdgcn_cvt_pk_f32_fp8(u3,  false); acc2 += g * ea[3];
        g = __builtin_amdgcn_cvt_pk_f32_fp8(u4,  false); acc2 += g * eb[0];
        g = __builtin_amdgcn_cvt_pk_f32_fp8(u5,  false); acc2 += g * eb[1];
        g = __builtin_amdgcn_cvt_pk_f32_fp8(u6,  false); acc2 += g * eb[2];
        g = __builtin_amdgcn_cvt_pk_f32_fp8(u7,  false); acc2 += g * eb[3];
        g = __builtin_amdgcn_cvt_pk_f32_fp8(u8,  false); acc2 += g * ec[0];
        g = __builtin_amdgcn_cvt_pk_f32_fp8(u9,  false); acc2 += g * ec[1];
        g = __builtin_amdgcn_cvt_pk_f32_fp8(u10, false); acc2 += g * ec[2];
        g = __builtin_amdgcn_cvt_pk_f32_fp8(u11, false); acc2 += g * ec[3];
        g = __builtin_amdgcn_cvt_pk_f32_fp8(u12, false); acc2 += g * ed[0];
        g = __builtin_amdgcn_cvt_pk_f32_fp8(u13, false); acc2 += g * ed[1];
        g = __builtin_amdgcn_cvt_pk_f32_fp8(u14, false); acc2 += g * ed[2];
        g = __builtin_amdgcn_cvt_pk_f32_fp8(u15, false); acc2 += g * ed[3];
    }
    if (j + 7 < degc) {   // one 8-edge chunk
        const unsigned co = cbase + (((unsigned)(j + el)) << 1);
        int ms0 = (int)CSRLD(co);
        float v0 = aLt + ARLD(ms0);
        v0 = v0 > 0.0f ? v0 : SLOPE * v0;
        float me0 = __expf(fminf(v0, 60.0f));
        serow[el] = me0;
        if (hh == 0) ssrc[wid][el] = ms0;
        __asm__ __volatile__("s_waitcnt lgkmcnt(0)" ::: "memory");
        floatx4 ea = *(const floatx4*)&serow[0];
        floatx4 eb = *(const floatx4*)&serow[4];
        intx4 sa = *(const intx4*)&ssrc[wid][0];
        intx4 sb = *(const intx4*)&ssrc[wid][4];
        unsigned short u0 = H8LD(sa[0]);
        unsigned short u1 = H8LD(sa[1]);
        unsigned short u2 = H8LD(sa[2]);
        unsigned short u3 = H8LD(sa[3]);
        unsigned short u4 = H8LD(sb[0]);
        unsigned short u5 = H8LD(sb[1]);
        unsigned short u6 = H8LD(sb[2]);
        unsigned short u7 = H8LD(sb[3]);
        den4 += ea; den4 += eb;
        floatx2 g;
        g = __builtin_amdgcn_cvt_pk_f32_fp8(u0, false); acc2 += g * ea[0];
        g = __builtin_amdgcn_cvt_pk_f32_fp8(u1, false); acc2 += g * ea[1];
        g = __builtin_amdgcn_cvt_pk_f32_fp8(u2, false); acc2 += g * ea[2];
        g = __builtin_amdgcn_cvt_pk_f32_fp8(u3, false); acc2 += g * ea[3];
        g = __builtin_amdgcn_cvt_pk_f32_fp8(u4, false); acc2 += g * eb[0];
        g = __builtin_amdgcn_cvt_pk_f32_fp8(u5, false); acc2 += g * eb[1];
        g = __builtin_amdgcn_cvt_pk_f32_fp8(u6, false); acc2 += g * eb[2];
        g = __builtin_amdgcn_cvt_pk_f32_fp8(u7, false); acc2 += g * eb[3];
        j += 8;
    }
    for (; j < degc; ++j) {   // tail: scalar path
        const unsigned co = cbase + (((unsigned)j) << 1);
        int s0 = (int)CSRLD(co);
        float v0 = aLt + ARLD(s0);
        v0 = v0 > 0.0f ? v0 : SLOPE * v0;
        float e0 = __expf(fminf(v0, 60.0f));
        unsigned short u0 = H8LD(s0);
        floatx2 g0 = __builtin_amdgcn_cvt_pk_f32_fp8(u0, false);
        dent += e0;
        acct0 = fmaf(e0, g0[0], acct0);
        acct1 = fmaf(e0, g0[1], acct1);
    }

    unsigned hv = __builtin_nontemporal_load(
        (const unsigned*)((const char*)h + (((size_t)n) << 8) + ((unsigned)c2 << 1)));
    float2 hs = __half22float2(*(const __half2*)&hv);
    float den = (den4[0] + den4[1]) + (den4[2] + den4[3]) + dent;
    float a0 = acc2[0] + acct0;
    float a1 = acc2[1] + acct1;
    float degf = (float)deg;
    float inv = (den > 0.0f) ? 1.0f / den : 0.0f;
    float o0 = fmaf(degf, hs.x, a0 * inv);
    float o1 = fmaf(degf, hs.y, a1 * inv);
    o0 = o0 > 0.0f ? o0 : __expf(o0) - 1.0f;   // ELU; exp(x)-1 accurate enough for x<0
    o1 = o1 > 0.0f ? o1 : __expf(o1) - 1.0f;
    floatx2 res = {o0, o1};    // ext_vector_type: valid operand for nontemporal builtin
    __builtin_nontemporal_store(res,
        (floatx2*)((char*)out + (((size_t)n) << 9) + ((unsigned)c2 << 2)));
}

extern "C" void kernel_launch(void* const* d_in, const int* in_sizes, int n_in,
                              void* d_out, int out_size, void* d_ws, size_t ws_size,
                              hipStream_t stream) {
    const float* X = (const float*)d_in[0];
    const int* ei  = (const int*)d_in[1];
    const float* W = (const float*)d_in[2];
    const float* B = (const float*)d_in[3];
    const float* A = (const float*)d_in[4];
    float* ws  = (float*)d_ws;
    __half* h  = (__half*)(ws + OFF_H);
    unsigned char* h8 = (unsigned char*)(ws + OFF_H8);
    float* al  = ws + OFF_AL;
    float* ar  = ws + OFF_AR;
    int* cur   = (int*)ws + OFF_CUR;
    unsigned short* csr = (unsigned short*)(ws + OFF_CSR);
    float* out = (float*)d_out;

    project_kernel<<<NTILES, 256, 0, stream>>>(X, W, B, A, h, h8, al, ar, cur);
    scatter_kernel<<<8 * SC_NCHUNK, 256, 0, stream>>>(ei, cur, csr);
    gather_kernel<<<(NN + 3) / 4, 256, 0, stream>>>(cur, csr, al, ar, h, h8, out);
}

// Round 6
// 154.235 us; speedup vs baseline: 1.2268x; 1.1540x over previous
//
#include <hip/hip_runtime.h>
#include <hip/hip_fp16.h>
#include <cmath>

#define NN 50000
#define NE 800000
#define SLOPE 0.2f
#define NTILES 782           // ceil(50000/64)
#define DSTRIDE 64           // fixed CSR slots per node (max expected degree ~36)

// workspace layout (4-byte units) — total ~33 MB
#define OFF_H    0           // __half h[NN*128]:    3,200,000 dwords
#define OFF_H8   3200000     // fp8 h8[NN*128]:      1,600,000 dwords
#define OFF_AL   4800000     // float al[NN*8]:        400,000
#define OFF_AR   5200000     // float ar[NN*8]:        400,000
#define OFF_CUR  5600000     // int cur[NN]:            50,000 (written by csr_kernel)
#define OFF_CSR  5650000     // ushort csr[NN*64]:   1,600,000 dwords
#define OFF_BKT  7250000     // u32 bkt[196*5120]:   1,003,520 dwords
#define OFF_BCNT 8253520     // int bcnt[196]

#define NBKT 196             // buckets of 256 target nodes (49999>>8 == 195)
#define BCAP 5120            // per-bucket capacity; mean 4096, +16 sigma

using half8   = __attribute__((ext_vector_type(8))) _Float16;
using floatx4 = __attribute__((ext_vector_type(4))) float;
using floatx2 = __attribute__((ext_vector_type(2))) float;
using intx4   = __attribute__((ext_vector_type(4))) int;

#define WST 136

// MFMA projection: h = fp16(X @ W^T + b), h8 = fp8(same); al/ar = attention dots.
// Also zeroes bcnt[] (kernel boundary orders it before bin_kernel's atomics).
__global__ __launch_bounds__(256) void project_kernel(
    const float* __restrict__ X,    // [NN,128]
    const float* __restrict__ W,    // [128,128] row-major W[o][k]
    const float* __restrict__ Bv,   // [128]
    const float* __restrict__ Av,   // [32]
    __half* __restrict__ h, unsigned char* __restrict__ h8,
    float* __restrict__ al, float* __restrict__ ar,
    int* __restrict__ bcnt)
{
    __shared__ _Float16 Wh[128 * WST];   // 34.8 KB
    __shared__ _Float16 Cs[64 * WST];    // 17.4 KB
    __shared__ float As[32];
    const int tid = threadIdx.x;
    const int bid = blockIdx.x;

    // zero bucket counters (replaces cur[] zeroing; cur is fully written by csr_kernel)
    if (bid == 0 && tid < NBKT) bcnt[tid] = 0;

    for (int i = tid; i < 128 * 128; i += 256) {
        int o = i >> 7, k = i & 127;
        Wh[o * WST + k] = (_Float16)W[i];
    }
    if (tid < 32) As[tid] = Av[tid];
    __syncthreads();

    const int wave = tid >> 6;
    const int lane = tid & 63;
    const int q = lane >> 4;
    const int n = lane & 15;
    const int gn = bid * 64 + wave * 16 + n;
    const bool valid = gn < NN;
    const float* xrow = X + ((long)gn << 7);

    half8 afrag[4];
#pragma unroll
    for (int kc = 0; kc < 4; ++kc) {
        float4 x0 = make_float4(0.f, 0.f, 0.f, 0.f), x1 = x0;
        if (valid) {
            x0 = *(const float4*)(xrow + kc * 32 + q * 8);
            x1 = *(const float4*)(xrow + kc * 32 + q * 8 + 4);
        }
        half8 a;
        a[0] = (_Float16)x0.x; a[1] = (_Float16)x0.y;
        a[2] = (_Float16)x0.z; a[3] = (_Float16)x0.w;
        a[4] = (_Float16)x1.x; a[5] = (_Float16)x1.y;
        a[6] = (_Float16)x1.z; a[7] = (_Float16)x1.w;
        afrag[kc] = a;
    }

    floatx4 acc[8];
#pragma unroll
    for (int nt = 0; nt < 8; ++nt) {
        float b = Bv[nt * 16 + n];
        acc[nt][0] = b; acc[nt][1] = b; acc[nt][2] = b; acc[nt][3] = b;
    }
#pragma unroll
    for (int nt = 0; nt < 8; ++nt) {
        const _Float16* wrow = &Wh[(nt * 16 + n) * WST];
#pragma unroll
        for (int kc = 0; kc < 4; ++kc) {
            half8 bfrag = *(const half8*)(wrow + kc * 32 + q * 8);
            acc[nt] = __builtin_amdgcn_mfma_f32_16x16x32_f16(afrag[kc], bfrag, acc[nt], 0, 0, 0);
        }
    }

    // C/D layout: lane holds C[m=q*4+r][n] -> Cs[node][feature]
    _Float16* cw = &Cs[(wave * 16) * WST];
#pragma unroll
    for (int nt = 0; nt < 8; ++nt) {
#pragma unroll
        for (int r = 0; r < 4; ++r) {
            cw[(q * 4 + r) * WST + nt * 16 + n] = (_Float16)acc[nt][r];
        }
    }
    __syncthreads();

    {   // h (fp16) + h8 (fp8): thread -> (node row = tid>>2, 32-feature chunk = tid&3)
        int rw = tid >> 2, ch = tid & 3;
        int gnode = bid * 64 + rw;
        if (gnode < NN) {
            const uint4* src = (const uint4*)&Cs[rw * WST + ch * 32];
            uint4 v[4] = { src[0], src[1], src[2], src[3] };
            uint4* dst = (uint4*)&h[((long)gnode << 7) + ch * 32];
            dst[0] = v[0]; dst[1] = v[1]; dst[2] = v[2]; dst[3] = v[3];

            const unsigned int* dw = (const unsigned int*)v;
            unsigned int res[8];
#pragma unroll
            for (int w = 0; w < 8; ++w) {
                unsigned int lo = dw[2 * w], hi = dw[2 * w + 1];
                float2 f0 = __half22float2(*(const __half2*)&lo);
                float2 f1 = __half22float2(*(const __half2*)&hi);
                unsigned int r = 0;
                r = __builtin_amdgcn_cvt_pk_fp8_f32(f0.x, f0.y, r, false);
                r = __builtin_amdgcn_cvt_pk_fp8_f32(f1.x, f1.y, r, true);
                res[w] = r;
            }
            uint4* d8 = (uint4*)&h8[((long)gnode << 7) + ch * 32];
            d8[0] = make_uint4(res[0], res[1], res[2], res[3]);
            d8[1] = make_uint4(res[4], res[5], res[6], res[7]);
        }
    }
    for (int p = tid; p < 512; p += 256) {   // al/ar: 64 nodes x 8 heads
        int nd = p >> 3, hh = p & 7;
        int gnode = bid * 64 + nd;
        if (gnode >= NN) continue;
        const _Float16* c = &Cs[nd * WST + hh * 16];
        float pL = 0.f, pR = 0.f;
#pragma unroll
        for (int f = 0; f < 16; ++f) {
            float hv = (float)c[f];
            pL = fmaf(hv, As[f], pL);
            pR = fmaf(hv, As[16 + f], pR);
        }
        al[gnode * 8 + hh] = pL;
        ar[gnode * 8 + hh] = pR;
    }
}

// ---------------------------------------------------------------------------
// scatter v3a — bin_kernel: partition edges into 196 buckets (tgt>>8) with LDS
// histogram + rank, one global atomic per (block,bucket) (~38K total vs 800K
// per-edge), LDS-reordered so bucket writes go out as coalesced runs.
// Packed edge u32 = (tgt<<16)|src (both < 65536).
// ---------------------------------------------------------------------------
__global__ __launch_bounds__(256) void bin_kernel(
    const int* __restrict__ ei, unsigned* __restrict__ bkt, int* __restrict__ bcnt)
{
    __shared__ unsigned hist[256];
    __shared__ unsigned scn[256];
    __shared__ unsigned gbase[256];
    __shared__ unsigned lbuf[4096];      // 16 KB reorder buffer
    const int tid = threadIdx.x, bid = blockIdx.x;
    hist[tid] = 0;
    __syncthreads();

    unsigned pk[16], rk[16];
#pragma unroll
    for (int it = 0; it < 4; ++it) {
        const int e0 = bid * 4096 + tid * 4 + it * 1024;
        if (e0 < NE) {   // NE%4==0 && e0%4==0 -> whole int4 group valid
            intx4 tg = *(const intx4*)(ei + NE + e0);
            intx4 sr = *(const intx4*)(ei + e0);
#pragma unroll
            for (int k = 0; k < 4; ++k) {
                unsigned p = ((unsigned)tg[k] << 16) | (unsigned)sr[k];
                pk[it * 4 + k] = p;
                rk[it * 4 + k] = atomicAdd(&hist[p >> 24], 1u);   // local rank in bucket
            }
        }
    }
    __syncthreads();

    // Hillis-Steele inclusive scan of hist -> scn, then make exclusive
    scn[tid] = hist[tid];
    __syncthreads();
    for (int ofs = 1; ofs < 256; ofs <<= 1) {
        unsigned v = scn[tid];
        unsigned a = (tid >= ofs) ? scn[tid - ofs] : 0u;
        __syncthreads();
        scn[tid] = v + a;
        __syncthreads();
    }
    {
        unsigned excl = scn[tid] - hist[tid];
        __syncthreads();
        scn[tid] = excl;
        __syncthreads();
    }

    // reserve global bucket ranges: ONE atomic per (block,bucket)
    if (tid < NBKT) gbase[tid] = hist[tid] ? (unsigned)atomicAdd(&bcnt[tid], (int)hist[tid]) : 0u;

    // scatter into LDS by bucket
#pragma unroll
    for (int it = 0; it < 4; ++it) {
        const int e0 = bid * 4096 + tid * 4 + it * 1024;
        if (e0 < NE) {
#pragma unroll
            for (int k = 0; k < 4; ++k) {
                unsigned p = pk[it * 4 + k];
                lbuf[scn[p >> 24] + rk[it * 4 + k]] = p;
            }
        }
    }
    __syncthreads();

    // coalesced copy-out: consecutive i within a bucket -> consecutive global
    const unsigned total = scn[255] + hist[255];
    for (unsigned i = tid; i < total; i += 256) {
        unsigned p = lbuf[i];
        unsigned b = p >> 24;
        unsigned pos = gbase[b] + (i - scn[b]);
        if (pos < BCAP) bkt[b * BCAP + pos] = p;
    }
}

// ---------------------------------------------------------------------------
// scatter v3b — csr_kernel: one block per bucket. Build the 256-node CSR slab
// entirely in LDS (32 KB) with LDS atomics only; write cur + csr rows as
// fully-coalesced contiguous stores. ZERO global atomics.
// ---------------------------------------------------------------------------
__global__ __launch_bounds__(256) void csr_kernel(
    const unsigned* __restrict__ bkt, const int* __restrict__ bcnt,
    int* __restrict__ cur, unsigned short* __restrict__ csr)
{
    __shared__ unsigned short csl[256 * DSTRIDE];   // 32 KB
    __shared__ unsigned cnt[256];
    const int tid = threadIdx.x, bin = blockIdx.x;
    cnt[tid] = 0;
    __syncthreads();

    const int m = min(bcnt[bin], BCAP);
    const unsigned* bp = bkt + (size_t)bin * BCAP;
    for (int i = tid; i < m; i += 256) {
        unsigned p = bp[i];
        unsigned local = (p >> 16) & 255u;          // node within bucket
        unsigned slot = atomicAdd(&cnt[local], 1u); // true-degree count
        if (slot < DSTRIDE) csl[(local << 6) + slot] = (unsigned short)(p & 0xFFFFu);
    }
    __syncthreads();

    const int gnode = bin * 256 + tid;
    if (gnode < NN) cur[gnode] = (int)cnt[tid];     // true degree (may exceed DSTRIDE)
    const int nrows = min(256, NN - bin * 256);     // last bucket: 80 rows
    uint4* dst = (uint4*)(csr + ((size_t)bin << 14));
    const uint4* srcp = (const uint4*)csl;
    for (int i = tid; i < nrows * 8; i += 256) dst[i] = srcp[i];
    // tails beyond cnt hold garbage; gather reads only j < min(deg,DSTRIDE)
}

// ---------------------------------------------------------------------------
// gather v3 (unchanged, verified r5): 16-edge chunks, SADDR offsets, packed fp32.
// ---------------------------------------------------------------------------
#define H8LD(s) (*(const unsigned short*)(h8 + ((((unsigned)(s)) << 7) | (unsigned)c2)))
#define ARLD(s) (*(const float*)((const char*)ar + ((((unsigned)(s)) << 5) | arof)))
#define CSRLD(o) (*(const unsigned short*)((const char*)csr + (o)))

__global__ __launch_bounds__(256) void gather_kernel(
    const int* __restrict__ cur, const unsigned short* __restrict__ csr,
    const float* __restrict__ al, const float* __restrict__ ar,
    const __half* __restrict__ h, const unsigned char* __restrict__ h8,
    float* __restrict__ out)
{
    __shared__ __align__(16) float se[4][160];    // 8 heads x stride 20
    __shared__ __align__(16) int ssrc[4][16];
    const int wid = threadIdx.x >> 6;
    const int n = blockIdx.x * 4 + wid;
    if (n >= NN) return;
    const int lane = threadIdx.x & 63;
    const int c2 = lane << 1;
    const int hh = lane >> 3;
    const int el = lane & 7;
    const int deg = cur[n];                 // true degree (skip term)
    const int degc = min(deg, DSTRIDE);     // iterated edges
    const unsigned cbase = ((unsigned)n) << 7;     // byte offset of node's csr row
    const unsigned arof = ((unsigned)hh) << 2;     // byte offset of head within ar row
    const float aLt = al[n * 8 + hh];
    float* serow = &se[wid][hh * 20];

    floatx2 acc2 = {0.f, 0.f};
    floatx4 den4 = {0.f, 0.f, 0.f, 0.f};
    float dent = 0.f;
    float acct0 = 0.f, acct1 = 0.f;
    int j = 0;
    for (; j + 15 < degc; j += 16) {
        const unsigned co = cbase + (((unsigned)(j + el)) << 1);
        int ms0 = (int)CSRLD(co);
        int ms1 = (int)CSRLD(co + 16u);
        float v0 = aLt + ARLD(ms0);
        float v1 = aLt + ARLD(ms1);
        v0 = v0 > 0.0f ? v0 : SLOPE * v0;
        v1 = v1 > 0.0f ? v1 : SLOPE * v1;
        float me0 = __expf(fminf(v0, 60.0f));
        float me1 = __expf(fminf(v1, 60.0f));
        serow[el] = me0;
        serow[8 + el] = me1;
        if (hh == 0) { ssrc[wid][el] = ms0; ssrc[wid][8 + el] = ms1; }
        // per-wave LDS reuse: DS ops are in-order within a wave; fence stops
        // compiler reordering. NO __syncthreads (waves have divergent trips).
        __asm__ __volatile__("s_waitcnt lgkmcnt(0)" ::: "memory");
        floatx4 ea = *(const floatx4*)&serow[0];
        floatx4 eb = *(const floatx4*)&serow[4];
        floatx4 ec = *(const floatx4*)&serow[8];
        floatx4 ed = *(const floatx4*)&serow[12];
        intx4 sa = *(const intx4*)&ssrc[wid][0];
        intx4 sb = *(const intx4*)&ssrc[wid][4];
        intx4 sc = *(const intx4*)&ssrc[wid][8];
        intx4 sd = *(const intx4*)&ssrc[wid][12];
        // 16 independent 2B loads, issued back-to-back (MLP)
        unsigned short u0  = H8LD(sa[0]);
        unsigned short u1  = H8LD(sa[1]);
        unsigned short u2  = H8LD(sa[2]);
        unsigned short u3  = H8LD(sa[3]);
        unsigned short u4  = H8LD(sb[0]);
        unsigned short u5  = H8LD(sb[1]);
        unsigned short u6  = H8LD(sb[2]);
        unsigned short u7  = H8LD(sb[3]);
        unsigned short u8  = H8LD(sc[0]);
        unsigned short u9  = H8LD(sc[1]);
        unsigned short u10 = H8LD(sc[2]);
        unsigned short u11 = H8LD(sc[3]);
        unsigned short u12 = H8LD(sd[0]);
        unsigned short u13 = H8LD(sd[1]);
        unsigned short u14 = H8LD(sd[2]);
        unsigned short u15 = H8LD(sd[3]);
        den4 += ea; den4 += eb; den4 += ec; den4 += ed;
        floatx2 g;
        g = __builtin_amdgcn_cvt_pk_f32_fp8(u0,  false); acc2 += g * ea[0];
        g = __builtin_amdgcn_cvt_pk_f32_fp8(u1,  false); acc2 += g * ea[1];
        g = __builtin_amdgcn_cvt_pk_f32_fp8(u2,  false); acc2 += g * ea[2];
        g = __builtin_amdgcn_cvt_pk_f32_fp8(u3,  false); acc2 += g * ea[3];
        g = __builtin_amdgcn_cvt_pk_f32_fp8(u4,  false); acc2 += g * eb[0];
        g = __builtin_amdgcn_cvt_pk_f32_fp8(u5,  false); acc2 += g * eb[1];
        g = __builtin_amdgcn_cvt_pk_f32_fp8(u6,  false); acc2 += g * eb[2];
        g = __builtin_amdgcn_cvt_pk_f32_fp8(u7,  false); acc2 += g * eb[3];
        g = __builtin_amdgcn_cvt_pk_f32_fp8(u8,  false); acc2 += g * ec[0];
        g = __builtin_amdgcn_cvt_pk_f32_fp8(u9,  false); acc2 += g * ec[1];
        g = __builtin_amdgcn_cvt_pk_f32_fp8(u10, false); acc2 += g * ec[2];
        g = __builtin_amdgcn_cvt_pk_f32_fp8(u11, false); acc2 += g * ec[3];
        g = __builtin_amdgcn_cvt_pk_f32_fp8(u12, false); acc2 += g * ed[0];
        g = __builtin_amdgcn_cvt_pk_f32_fp8(u13, false); acc2 += g * ed[1];
        g = __builtin_amdgcn_cvt_pk_f32_fp8(u14, false); acc2 += g * ed[2];
        g = __builtin_amdgcn_cvt_pk_f32_fp8(u15, false); acc2 += g * ed[3];
    }
    if (j + 7 < degc) {   // one 8-edge chunk
        const unsigned co = cbase + (((unsigned)(j + el)) << 1);
        int ms0 = (int)CSRLD(co);
        float v0 = aLt + ARLD(ms0);
        v0 = v0 > 0.0f ? v0 : SLOPE * v0;
        float me0 = __expf(fminf(v0, 60.0f));
        serow[el] = me0;
        if (hh == 0) ssrc[wid][el] = ms0;
        __asm__ __volatile__("s_waitcnt lgkmcnt(0)" ::: "memory");
        floatx4 ea = *(const floatx4*)&serow[0];
        floatx4 eb = *(const floatx4*)&serow[4];
        intx4 sa = *(const intx4*)&ssrc[wid][0];
        intx4 sb = *(const intx4*)&ssrc[wid][4];
        unsigned short u0 = H8LD(sa[0]);
        unsigned short u1 = H8LD(sa[1]);
        unsigned short u2 = H8LD(sa[2]);
        unsigned short u3 = H8LD(sa[3]);
        unsigned short u4 = H8LD(sb[0]);
        unsigned short u5 = H8LD(sb[1]);
        unsigned short u6 = H8LD(sb[2]);
        unsigned short u7 = H8LD(sb[3]);
        den4 += ea; den4 += eb;
        floatx2 g;
        g = __builtin_amdgcn_cvt_pk_f32_fp8(u0, false); acc2 += g * ea[0];
        g = __builtin_amdgcn_cvt_pk_f32_fp8(u1, false); acc2 += g * ea[1];
        g = __builtin_amdgcn_cvt_pk_f32_fp8(u2, false); acc2 += g * ea[2];
        g = __builtin_amdgcn_cvt_pk_f32_fp8(u3, false); acc2 += g * ea[3];
        g = __builtin_amdgcn_cvt_pk_f32_fp8(u4, false); acc2 += g * eb[0];
        g = __builtin_amdgcn_cvt_pk_f32_fp8(u5, false); acc2 += g * eb[1];
        g = __builtin_amdgcn_cvt_pk_f32_fp8(u6, false); acc2 += g * eb[2];
        g = __builtin_amdgcn_cvt_pk_f32_fp8(u7, false); acc2 += g * eb[3];
        j += 8;
    }
    for (; j < degc; ++j) {   // tail: scalar path
        const unsigned co = cbase + (((unsigned)j) << 1);
        int s0 = (int)CSRLD(co);
        float v0 = aLt + ARLD(s0);
        v0 = v0 > 0.0f ? v0 : SLOPE * v0;
        float e0 = __expf(fminf(v0, 60.0f));
        unsigned short u0 = H8LD(s0);
        floatx2 g0 = __builtin_amdgcn_cvt_pk_f32_fp8(u0, false);
        dent += e0;
        acct0 = fmaf(e0, g0[0], acct0);
        acct1 = fmaf(e0, g0[1], acct1);
    }

    unsigned hv = __builtin_nontemporal_load(
        (const unsigned*)((const char*)h + (((size_t)n) << 8) + ((unsigned)c2 << 1)));
    float2 hs = __half22float2(*(const __half2*)&hv);
    float den = (den4[0] + den4[1]) + (den4[2] + den4[3]) + dent;
    float a0 = acc2[0] + acct0;
    float a1 = acc2[1] + acct1;
    float degf = (float)deg;
    float inv = (den > 0.0f) ? 1.0f / den : 0.0f;
    float o0 = fmaf(degf, hs.x, a0 * inv);
    float o1 = fmaf(degf, hs.y, a1 * inv);
    o0 = o0 > 0.0f ? o0 : __expf(o0) - 1.0f;   // ELU; exp(x)-1 accurate enough for x<0
    o1 = o1 > 0.0f ? o1 : __expf(o1) - 1.0f;
    floatx2 res = {o0, o1};    // ext_vector_type: valid operand for nontemporal builtin
    __builtin_nontemporal_store(res,
        (floatx2*)((char*)out + (((size_t)n) << 9) + ((unsigned)c2 << 2)));
}

extern "C" void kernel_launch(void* const* d_in, const int* in_sizes, int n_in,
                              void* d_out, int out_size, void* d_ws, size_t ws_size,
                              hipStream_t stream) {
    const float* X = (const float*)d_in[0];
    const int* ei  = (const int*)d_in[1];
    const float* W = (const float*)d_in[2];
    const float* B = (const float*)d_in[3];
    const float* A = (const float*)d_in[4];
    float* ws  = (float*)d_ws;
    __half* h  = (__half*)(ws + OFF_H);
    unsigned char* h8 = (unsigned char*)(ws + OFF_H8);
    float* al  = ws + OFF_AL;
    float* ar  = ws + OFF_AR;
    int* cur   = (int*)ws + OFF_CUR;
    unsigned short* csr = (unsigned short*)(ws + OFF_CSR);
    unsigned* bkt = (unsigned*)(ws + OFF_BKT);
    int* bcnt  = (int*)ws + OFF_BCNT;
    float* out = (float*)d_out;

    project_kernel<<<NTILES, 256, 0, stream>>>(X, W, B, A, h, h8, al, ar, bcnt);
    bin_kernel<<<NBKT, 256, 0, stream>>>(ei, bkt, bcnt);
    csr_kernel<<<NBKT, 256, 0, stream>>>(bkt, bcnt, cur, csr);
    gather_kernel<<<(NN + 3) / 4, 256, 0, stream>>>(cur, csr, al, ar, h, h8, out);
}

// Round 7
// 142.193 us; speedup vs baseline: 1.3307x; 1.0847x over previous
//
#include <hip/hip_runtime.h>
#include <hip/hip_fp16.h>
#include <cmath>

#define NN 50000
#define NE 800000
#define SLOPE 0.2f
#define NTILES 782           // ceil(50000/64)
#define DSTRIDE 64           // fixed CSR slots per node (max expected degree ~36)

// workspace layout (4-byte units) — total ~33 MB
#define OFF_H    0           // __half h[NN*128]:    3,200,000 dwords
#define OFF_H8   3200000     // fp8 h8[NN*128]:      1,600,000 dwords
#define OFF_AL   4800000     // float al[NN*8]:        400,000
#define OFF_AR   5200000     // float ar[NN*8]:        400,000
#define OFF_CUR  5600000     // int cur[NN]:            50,000 (written by csr_kernel)
#define OFF_CSR  5650000     // ushort csr[NN*64]:   1,600,000 dwords
#define OFF_BKT  7250000     // u32 bkt[196*5120]:   1,003,520 dwords
#define OFF_BCNT 8253520     // int bcnt[196]

#define NBKT 196             // buckets of 256 target nodes (49999>>8 == 195)
#define BCAP 5120            // per-bucket capacity; mean 4096, +16 sigma

using half8   = __attribute__((ext_vector_type(8))) _Float16;
using floatx4 = __attribute__((ext_vector_type(4))) float;
using floatx2 = __attribute__((ext_vector_type(2))) float;
using intx4   = __attribute__((ext_vector_type(4))) int;

#define WST 136

// MFMA projection: h = fp16(X @ W^T + b), h8 = fp8(same); al/ar = attention dots.
// Also zeroes bcnt[] (kernel boundary orders it before bin_kernel's atomics).
__global__ __launch_bounds__(256) void project_kernel(
    const float* __restrict__ X,    // [NN,128]
    const float* __restrict__ W,    // [128,128] row-major W[o][k]
    const float* __restrict__ Bv,   // [128]
    const float* __restrict__ Av,   // [32]
    __half* __restrict__ h, unsigned char* __restrict__ h8,
    float* __restrict__ al, float* __restrict__ ar,
    int* __restrict__ bcnt)
{
    __shared__ _Float16 Wh[128 * WST];   // 34.8 KB
    __shared__ _Float16 Cs[64 * WST];    // 17.4 KB
    __shared__ float As[32];
    const int tid = threadIdx.x;
    const int bid = blockIdx.x;

    // zero bucket counters (replaces cur[] zeroing; cur is fully written by csr_kernel)
    if (bid == 0 && tid < NBKT) bcnt[tid] = 0;

    for (int i = tid; i < 128 * 128; i += 256) {
        int o = i >> 7, k = i & 127;
        Wh[o * WST + k] = (_Float16)W[i];
    }
    if (tid < 32) As[tid] = Av[tid];
    __syncthreads();

    const int wave = tid >> 6;
    const int lane = tid & 63;
    const int q = lane >> 4;
    const int n = lane & 15;
    const int gn = bid * 64 + wave * 16 + n;
    const bool valid = gn < NN;
    const float* xrow = X + ((long)gn << 7);

    half8 afrag[4];
#pragma unroll
    for (int kc = 0; kc < 4; ++kc) {
        float4 x0 = make_float4(0.f, 0.f, 0.f, 0.f), x1 = x0;
        if (valid) {
            x0 = *(const float4*)(xrow + kc * 32 + q * 8);
            x1 = *(const float4*)(xrow + kc * 32 + q * 8 + 4);
        }
        half8 a;
        a[0] = (_Float16)x0.x; a[1] = (_Float16)x0.y;
        a[2] = (_Float16)x0.z; a[3] = (_Float16)x0.w;
        a[4] = (_Float16)x1.x; a[5] = (_Float16)x1.y;
        a[6] = (_Float16)x1.z; a[7] = (_Float16)x1.w;
        afrag[kc] = a;
    }

    floatx4 acc[8];
#pragma unroll
    for (int nt = 0; nt < 8; ++nt) {
        float b = Bv[nt * 16 + n];
        acc[nt][0] = b; acc[nt][1] = b; acc[nt][2] = b; acc[nt][3] = b;
    }
#pragma unroll
    for (int nt = 0; nt < 8; ++nt) {
        const _Float16* wrow = &Wh[(nt * 16 + n) * WST];
#pragma unroll
        for (int kc = 0; kc < 4; ++kc) {
            half8 bfrag = *(const half8*)(wrow + kc * 32 + q * 8);
            acc[nt] = __builtin_amdgcn_mfma_f32_16x16x32_f16(afrag[kc], bfrag, acc[nt], 0, 0, 0);
        }
    }

    // C/D layout: lane holds C[m=q*4+r][n] -> Cs[node][feature]
    _Float16* cw = &Cs[(wave * 16) * WST];
#pragma unroll
    for (int nt = 0; nt < 8; ++nt) {
#pragma unroll
        for (int r = 0; r < 4; ++r) {
            cw[(q * 4 + r) * WST + nt * 16 + n] = (_Float16)acc[nt][r];
        }
    }
    __syncthreads();

    {   // h (fp16) + h8 (fp8): thread -> (node row = tid>>2, 32-feature chunk = tid&3)
        int rw = tid >> 2, ch = tid & 3;
        int gnode = bid * 64 + rw;
        if (gnode < NN) {
            const uint4* src = (const uint4*)&Cs[rw * WST + ch * 32];
            uint4 v[4] = { src[0], src[1], src[2], src[3] };
            uint4* dst = (uint4*)&h[((long)gnode << 7) + ch * 32];
            dst[0] = v[0]; dst[1] = v[1]; dst[2] = v[2]; dst[3] = v[3];

            const unsigned int* dw = (const unsigned int*)v;
            unsigned int res[8];
#pragma unroll
            for (int w = 0; w < 8; ++w) {
                unsigned int lo = dw[2 * w], hi = dw[2 * w + 1];
                float2 f0 = __half22float2(*(const __half2*)&lo);
                float2 f1 = __half22float2(*(const __half2*)&hi);
                unsigned int r = 0;
                r = __builtin_amdgcn_cvt_pk_fp8_f32(f0.x, f0.y, r, false);
                r = __builtin_amdgcn_cvt_pk_fp8_f32(f1.x, f1.y, r, true);
                res[w] = r;
            }
            uint4* d8 = (uint4*)&h8[((long)gnode << 7) + ch * 32];
            d8[0] = make_uint4(res[0], res[1], res[2], res[3]);
            d8[1] = make_uint4(res[4], res[5], res[6], res[7]);
        }
    }
    for (int p = tid; p < 512; p += 256) {   // al/ar: 64 nodes x 8 heads
        int nd = p >> 3, hh = p & 7;
        int gnode = bid * 64 + nd;
        if (gnode >= NN) continue;
        const _Float16* c = &Cs[nd * WST + hh * 16];
        float pL = 0.f, pR = 0.f;
#pragma unroll
        for (int f = 0; f < 16; ++f) {
            float hv = (float)c[f];
            pL = fmaf(hv, As[f], pL);
            pR = fmaf(hv, As[16 + f], pR);
        }
        al[gnode * 8 + hh] = pL;
        ar[gnode * 8 + hh] = pR;
    }
}

// ---------------------------------------------------------------------------
// scatter v3a — bin_kernel: partition edges into 196 buckets (tgt>>8) with LDS
// histogram + rank, one global atomic per (block,bucket) (~38K total vs 800K
// per-edge), LDS-reordered so bucket writes go out as coalesced runs.
// Packed edge u32 = (tgt<<16)|src (both < 65536).
// ---------------------------------------------------------------------------
__global__ __launch_bounds__(256) void bin_kernel(
    const int* __restrict__ ei, unsigned* __restrict__ bkt, int* __restrict__ bcnt)
{
    __shared__ unsigned hist[256];
    __shared__ unsigned scn[256];
    __shared__ unsigned gbase[256];
    __shared__ unsigned lbuf[4096];      // 16 KB reorder buffer
    const int tid = threadIdx.x, bid = blockIdx.x;
    hist[tid] = 0;
    __syncthreads();

    unsigned pk[16], rk[16];
#pragma unroll
    for (int it = 0; it < 4; ++it) {
        const int e0 = bid * 4096 + tid * 4 + it * 1024;
        if (e0 < NE) {   // NE%4==0 && e0%4==0 -> whole int4 group valid
            intx4 tg = *(const intx4*)(ei + NE + e0);
            intx4 sr = *(const intx4*)(ei + e0);
#pragma unroll
            for (int k = 0; k < 4; ++k) {
                unsigned p = ((unsigned)tg[k] << 16) | (unsigned)sr[k];
                pk[it * 4 + k] = p;
                rk[it * 4 + k] = atomicAdd(&hist[p >> 24], 1u);   // local rank in bucket
            }
        }
    }
    __syncthreads();

    // Hillis-Steele inclusive scan of hist -> scn, then make exclusive
    scn[tid] = hist[tid];
    __syncthreads();
    for (int ofs = 1; ofs < 256; ofs <<= 1) {
        unsigned v = scn[tid];
        unsigned a = (tid >= ofs) ? scn[tid - ofs] : 0u;
        __syncthreads();
        scn[tid] = v + a;
        __syncthreads();
    }
    {
        unsigned excl = scn[tid] - hist[tid];
        __syncthreads();
        scn[tid] = excl;
        __syncthreads();
    }

    // reserve global bucket ranges: ONE atomic per (block,bucket)
    if (tid < NBKT) gbase[tid] = hist[tid] ? (unsigned)atomicAdd(&bcnt[tid], (int)hist[tid]) : 0u;

    // scatter into LDS by bucket
#pragma unroll
    for (int it = 0; it < 4; ++it) {
        const int e0 = bid * 4096 + tid * 4 + it * 1024;
        if (e0 < NE) {
#pragma unroll
            for (int k = 0; k < 4; ++k) {
                unsigned p = pk[it * 4 + k];
                lbuf[scn[p >> 24] + rk[it * 4 + k]] = p;
            }
        }
    }
    __syncthreads();

    // coalesced copy-out: consecutive i within a bucket -> consecutive global
    const unsigned total = scn[255] + hist[255];
    for (unsigned i = tid; i < total; i += 256) {
        unsigned p = lbuf[i];
        unsigned b = p >> 24;
        unsigned pos = gbase[b] + (i - scn[b]);
        if (pos < BCAP) bkt[b * BCAP + pos] = p;
    }
}

// ---------------------------------------------------------------------------
// scatter v3b — csr_kernel: one block per bucket. Build the 256-node CSR slab
// entirely in LDS (32 KB) with LDS atomics only; write cur + csr rows as
// fully-coalesced contiguous stores. ZERO global atomics.
// ---------------------------------------------------------------------------
__global__ __launch_bounds__(256) void csr_kernel(
    const unsigned* __restrict__ bkt, const int* __restrict__ bcnt,
    int* __restrict__ cur, unsigned short* __restrict__ csr)
{
    __shared__ unsigned short csl[256 * DSTRIDE];   // 32 KB
    __shared__ unsigned cnt[256];
    const int tid = threadIdx.x, bin = blockIdx.x;
    cnt[tid] = 0;
    __syncthreads();

    const int m = min(bcnt[bin], BCAP);
    const unsigned* bp = bkt + (size_t)bin * BCAP;
    for (int i = tid; i < m; i += 256) {
        unsigned p = bp[i];
        unsigned local = (p >> 16) & 255u;          // node within bucket
        unsigned slot = atomicAdd(&cnt[local], 1u); // true-degree count
        if (slot < DSTRIDE) csl[(local << 6) + slot] = (unsigned short)(p & 0xFFFFu);
    }
    __syncthreads();

    const int gnode = bin * 256 + tid;
    if (gnode < NN) cur[gnode] = (int)cnt[tid];     // true degree (may exceed DSTRIDE)
    const int nrows = min(256, NN - bin * 256);     // last bucket: 80 rows
    uint4* dst = (uint4*)(csr + ((size_t)bin << 14));
    const uint4* srcp = (const uint4*)csl;
    for (int i = tid; i < nrows * 8; i += 256) dst[i] = srcp[i];
    // tails beyond cnt hold garbage; gather reads only j < min(deg,DSTRIDE)
}

// ---------------------------------------------------------------------------
// gather v4: single fully-masked 16-edge chunk loop — no 8-chunk, no scalar
// tail. Old v3 paid a FULL serial latency chain (csr->ar->exp->h8) per tail
// edge (avg ~3.5/node with Poisson(16) degrees) = ~40% of gather time. Now
// invalid lanes force src=0 (row 0 is real data: finite fp8/ar; masking only
// the weight would let garbage-fp8 NaN poison acc via NaN*0) and me=0 (zero
// contribution to den/acc). deg<=16 nodes (57%) run exactly one chunk.
// Masked loop never reads past csr slot 63 (j<=48, slot<=63).
// ---------------------------------------------------------------------------
#define H8LD(s) (*(const unsigned short*)(h8 + ((((unsigned)(s)) << 7) | (unsigned)c2)))
#define ARLD(s) (*(const float*)((const char*)ar + ((((unsigned)(s)) << 5) | arof)))
#define CSRLD(o) (*(const unsigned short*)((const char*)csr + (o)))

__global__ __launch_bounds__(256) void gather_kernel(
    const int* __restrict__ cur, const unsigned short* __restrict__ csr,
    const float* __restrict__ al, const float* __restrict__ ar,
    const __half* __restrict__ h, const unsigned char* __restrict__ h8,
    float* __restrict__ out)
{
    __shared__ __align__(16) float se[4][160];    // 8 heads x stride 20
    __shared__ __align__(16) int ssrc[4][16];
    const int wid = threadIdx.x >> 6;
    const int n = blockIdx.x * 4 + wid;
    if (n >= NN) return;
    const int lane = threadIdx.x & 63;
    const int c2 = lane << 1;
    const int hh = lane >> 3;
    const int el = lane & 7;
    const int deg = cur[n];                 // true degree (skip term)
    const int degc = min(deg, DSTRIDE);     // iterated edges
    const unsigned cbase = ((unsigned)n) << 7;     // byte offset of node's csr row
    const unsigned arof = ((unsigned)hh) << 2;     // byte offset of head within ar row
    const float aLt = al[n * 8 + hh];
    float* serow = &se[wid][hh * 20];

    floatx2 acc2 = {0.f, 0.f};
    floatx4 den4 = {0.f, 0.f, 0.f, 0.f};
    for (int j = 0; j < degc; j += 16) {
        const bool va = (j + el) < degc;
        const bool vb = (j + 8 + el) < degc;
        const unsigned co = cbase + (((unsigned)(j + el)) << 1);
        int ms0 = va ? (int)CSRLD(co) : 0;          // masked index: row 0 = real, finite data
        int ms1 = vb ? (int)CSRLD(co + 16u) : 0;
        float v0 = aLt + ARLD(ms0);
        float v1 = aLt + ARLD(ms1);
        v0 = v0 > 0.0f ? v0 : SLOPE * v0;
        v1 = v1 > 0.0f ? v1 : SLOPE * v1;
        float me0 = va ? __expf(fminf(v0, 60.0f)) : 0.0f;
        float me1 = vb ? __expf(fminf(v1, 60.0f)) : 0.0f;
        serow[el] = me0;
        serow[8 + el] = me1;
        if (hh == 0) { ssrc[wid][el] = ms0; ssrc[wid][8 + el] = ms1; }
        // per-wave LDS reuse: DS ops are in-order within a wave; fence stops
        // compiler reordering. NO __syncthreads (waves have divergent trips).
        __asm__ __volatile__("s_waitcnt lgkmcnt(0)" ::: "memory");
        floatx4 ea = *(const floatx4*)&serow[0];
        floatx4 eb = *(const floatx4*)&serow[4];
        floatx4 ec = *(const floatx4*)&serow[8];
        floatx4 ed = *(const floatx4*)&serow[12];
        intx4 sa = *(const intx4*)&ssrc[wid][0];
        intx4 sb = *(const intx4*)&ssrc[wid][4];
        intx4 sc = *(const intx4*)&ssrc[wid][8];
        intx4 sd = *(const intx4*)&ssrc[wid][12];
        // 16 independent 2B loads, issued back-to-back (MLP); each is a
        // wave-coalesced 128B row read (uniform row, lane*2 offset)
        unsigned short u0  = H8LD(sa[0]);
        unsigned short u1  = H8LD(sa[1]);
        unsigned short u2  = H8LD(sa[2]);
        unsigned short u3  = H8LD(sa[3]);
        unsigned short u4  = H8LD(sb[0]);
        unsigned short u5  = H8LD(sb[1]);
        unsigned short u6  = H8LD(sb[2]);
        unsigned short u7  = H8LD(sb[3]);
        unsigned short u8  = H8LD(sc[0]);
        unsigned short u9  = H8LD(sc[1]);
        unsigned short u10 = H8LD(sc[2]);
        unsigned short u11 = H8LD(sc[3]);
        unsigned short u12 = H8LD(sd[0]);
        unsigned short u13 = H8LD(sd[1]);
        unsigned short u14 = H8LD(sd[2]);
        unsigned short u15 = H8LD(sd[3]);
        den4 += ea; den4 += eb; den4 += ec; den4 += ed;
        floatx2 g;
        g = __builtin_amdgcn_cvt_pk_f32_fp8(u0,  false); acc2 += g * ea[0];
        g = __builtin_amdgcn_cvt_pk_f32_fp8(u1,  false); acc2 += g * ea[1];
        g = __builtin_amdgcn_cvt_pk_f32_fp8(u2,  false); acc2 += g * ea[2];
        g = __builtin_amdgcn_cvt_pk_f32_fp8(u3,  false); acc2 += g * ea[3];
        g = __builtin_amdgcn_cvt_pk_f32_fp8(u4,  false); acc2 += g * eb[0];
        g = __builtin_amdgcn_cvt_pk_f32_fp8(u5,  false); acc2 += g * eb[1];
        g = __builtin_amdgcn_cvt_pk_f32_fp8(u6,  false); acc2 += g * eb[2];
        g = __builtin_amdgcn_cvt_pk_f32_fp8(u7,  false); acc2 += g * eb[3];
        g = __builtin_amdgcn_cvt_pk_f32_fp8(u8,  false); acc2 += g * ec[0];
        g = __builtin_amdgcn_cvt_pk_f32_fp8(u9,  false); acc2 += g * ec[1];
        g = __builtin_amdgcn_cvt_pk_f32_fp8(u10, false); acc2 += g * ec[2];
        g = __builtin_amdgcn_cvt_pk_f32_fp8(u11, false); acc2 += g * ec[3];
        g = __builtin_amdgcn_cvt_pk_f32_fp8(u12, false); acc2 += g * ed[0];
        g = __builtin_amdgcn_cvt_pk_f32_fp8(u13, false); acc2 += g * ed[1];
        g = __builtin_amdgcn_cvt_pk_f32_fp8(u14, false); acc2 += g * ed[2];
        g = __builtin_amdgcn_cvt_pk_f32_fp8(u15, false); acc2 += g * ed[3];
    }

    unsigned hv = __builtin_nontemporal_load(
        (const unsigned*)((const char*)h + (((size_t)n) << 8) + ((unsigned)c2 << 1)));
    float2 hs = __half22float2(*(const __half2*)&hv);
    float den = (den4[0] + den4[1]) + (den4[2] + den4[3]);
    float degf = (float)deg;
    float inv = (den > 0.0f) ? 1.0f / den : 0.0f;
    float o0 = fmaf(degf, hs.x, acc2[0] * inv);
    float o1 = fmaf(degf, hs.y, acc2[1] * inv);
    o0 = o0 > 0.0f ? o0 : __expf(o0) - 1.0f;   // ELU; exp(x)-1 accurate enough for x<0
    o1 = o1 > 0.0f ? o1 : __expf(o1) - 1.0f;
    floatx2 res = {o0, o1};    // ext_vector_type: valid operand for nontemporal builtin
    __builtin_nontemporal_store(res,
        (floatx2*)((char*)out + (((size_t)n) << 9) + ((unsigned)c2 << 2)));
}

extern "C" void kernel_launch(void* const* d_in, const int* in_sizes, int n_in,
                              void* d_out, int out_size, void* d_ws, size_t ws_size,
                              hipStream_t stream) {
    const float* X = (const float*)d_in[0];
    const int* ei  = (const int*)d_in[1];
    const float* W = (const float*)d_in[2];
    const float* B = (const float*)d_in[3];
    const float* A = (const float*)d_in[4];
    float* ws  = (float*)d_ws;
    __half* h  = (__half*)(ws + OFF_H);
    unsigned char* h8 = (unsigned char*)(ws + OFF_H8);
    float* al  = ws + OFF_AL;
    float* ar  = ws + OFF_AR;
    int* cur   = (int*)ws + OFF_CUR;
    unsigned short* csr = (unsigned short*)(ws + OFF_CSR);
    unsigned* bkt = (unsigned*)(ws + OFF_BKT);
    int* bcnt  = (int*)ws + OFF_BCNT;
    float* out = (float*)d_out;

    project_kernel<<<NTILES, 256, 0, stream>>>(X, W, B, A, h, h8, al, ar, bcnt);
    bin_kernel<<<NBKT, 256, 0, stream>>>(ei, bkt, bcnt);
    csr_kernel<<<NBKT, 256, 0, stream>>>(bkt, bcnt, cur, csr);
    gather_kernel<<<(NN + 3) / 4, 256, 0, stream>>>(cur, csr, al, ar, h, h8, out);
}

// Round 9
// 141.040 us; speedup vs baseline: 1.3416x; 1.0082x over previous
//
#include <hip/hip_runtime.h>
#include <hip/hip_fp16.h>
#include <cmath>

#define NN 50000
#define NE 800000
#define SLOPE 0.2f
#define NTILES 782           // ceil(50000/64)
#define DSTRIDE 64           // fixed CSR slots per node (max expected degree ~36)

#define NBKT 196             // buckets of 256 target nodes (49999>>8 == 195)
#define NCHK 196             // bin chunks of 4096 edges
#define BINCAP 64            // per-(chunk,bucket) capacity; mean 21, P(overflow)~1e-8

// workspace layout (4-byte units) — total ~39 MB
#define OFF_H    0           // __half h[NN*128]:    3,200,000 dwords
#define OFF_H8   3200000     // fp8 h8[NN*128]:      1,600,000 dwords
#define OFF_AL   4800000     // float al[NN*8]:        400,000
#define OFF_AR   5200000     // float ar[NN*8]:        400,000
#define OFF_CUR  5600000     // int cur[NN]:            50,000 (written by csr_kernel)
#define OFF_CSR  5650000     // ushort csr[NN*64]:   1,600,000 dwords
#define OFF_BKT  7250000     // u32 bkt[196*196*64]: 2,458,624 dwords
#define OFF_CNTS 9708624     // u32 cnts[196*196]:      38,416 dwords

using half8   = __attribute__((ext_vector_type(8))) _Float16;
using floatx4 = __attribute__((ext_vector_type(4))) float;
using floatx2 = __attribute__((ext_vector_type(2))) float;
using intx4   = __attribute__((ext_vector_type(4))) int;

#define WST 136

// ---------------------------------------------------------------------------
// fused project+bin: blocks [0,NTILES) do the MFMA projection; blocks
// [NTILES, NTILES+NCHK) bin 4096 edges each into deterministic per-
// (chunk,bucket) regions — NO global atomics, NO scan, no bcnt zeroing.
// Bin reads only ei (independent of projection) so its memory work hides
// under project's MFMA phase instead of owning a separate launch.
// ---------------------------------------------------------------------------
__global__ __launch_bounds__(256) void project_bin_kernel(
    const float* __restrict__ X,    // [NN,128]
    const float* __restrict__ W,    // [128,128] row-major W[o][k]
    const float* __restrict__ Bv,   // [128]
    const float* __restrict__ Av,   // [32]
    const int* __restrict__ ei,     // [2,NE]
    __half* __restrict__ h, unsigned char* __restrict__ h8,
    float* __restrict__ al, float* __restrict__ ar,
    unsigned* __restrict__ bkt, unsigned* __restrict__ cnts)
{
    __shared__ _Float16 Wh[128 * WST];   // 34.8 KB
    __shared__ _Float16 Cs[64 * WST];    // 17.4 KB
    __shared__ float As[32];
    __shared__ unsigned bincnt[NBKT];    // bin role only
    const int tid = threadIdx.x;
    const int bid = blockIdx.x;

    if (bid >= NTILES) {   // ---- bin role ----
        const int c = bid - NTILES;      // chunk index
        if (tid < NBKT) bincnt[tid] = 0;
        __syncthreads();
#pragma unroll
        for (int it = 0; it < 4; ++it) {
            const int e0 = c * 4096 + tid * 4 + it * 1024;
            if (e0 < NE) {   // NE%4==0 && e0%4==0 -> whole int4 group valid
                intx4 tg = *(const intx4*)(ei + NE + e0);
                intx4 sr = *(const intx4*)(ei + e0);
#pragma unroll
                for (int k = 0; k < 4; ++k) {
                    unsigned p = ((unsigned)tg[k] << 16) | (unsigned)sr[k];
                    unsigned b = p >> 24;                       // tgt>>8
                    unsigned slot = atomicAdd(&bincnt[b], 1u);  // LDS only
                    if (slot < BINCAP)
                        bkt[(((unsigned)c * NBKT + b) << 6) + slot] = p;
                }
            }
        }
        __syncthreads();
        if (tid < NBKT) cnts[c * NBKT + tid] = bincnt[tid];     // coalesced row
        return;
    }

    // ---- project role (unchanged) ----
    for (int i = tid; i < 128 * 128; i += 256) {
        int o = i >> 7, k = i & 127;
        Wh[o * WST + k] = (_Float16)W[i];
    }
    if (tid < 32) As[tid] = Av[tid];
    __syncthreads();

    const int wave = tid >> 6;
    const int lane = tid & 63;
    const int q = lane >> 4;
    const int n = lane & 15;
    const int gn = bid * 64 + wave * 16 + n;
    const bool valid = gn < NN;
    const float* xrow = X + ((long)gn << 7);

    half8 afrag[4];
#pragma unroll
    for (int kc = 0; kc < 4; ++kc) {
        float4 x0 = make_float4(0.f, 0.f, 0.f, 0.f), x1 = x0;
        if (valid) {
            x0 = *(const float4*)(xrow + kc * 32 + q * 8);
            x1 = *(const float4*)(xrow + kc * 32 + q * 8 + 4);
        }
        half8 a;
        a[0] = (_Float16)x0.x; a[1] = (_Float16)x0.y;
        a[2] = (_Float16)x0.z; a[3] = (_Float16)x0.w;
        a[4] = (_Float16)x1.x; a[5] = (_Float16)x1.y;
        a[6] = (_Float16)x1.z; a[7] = (_Float16)x1.w;
        afrag[kc] = a;
    }

    floatx4 acc[8];
#pragma unroll
    for (int nt = 0; nt < 8; ++nt) {
        float b = Bv[nt * 16 + n];
        acc[nt][0] = b; acc[nt][1] = b; acc[nt][2] = b; acc[nt][3] = b;
    }
#pragma unroll
    for (int nt = 0; nt < 8; ++nt) {
        const _Float16* wrow = &Wh[(nt * 16 + n) * WST];
#pragma unroll
        for (int kc = 0; kc < 4; ++kc) {
            half8 bfrag = *(const half8*)(wrow + kc * 32 + q * 8);
            acc[nt] = __builtin_amdgcn_mfma_f32_16x16x32_f16(afrag[kc], bfrag, acc[nt], 0, 0, 0);
        }
    }

    // C/D layout: lane holds C[m=q*4+r][n] -> Cs[node][feature]
    _Float16* cw = &Cs[(wave * 16) * WST];
#pragma unroll
    for (int nt = 0; nt < 8; ++nt) {
#pragma unroll
        for (int r = 0; r < 4; ++r) {
            cw[(q * 4 + r) * WST + nt * 16 + n] = (_Float16)acc[nt][r];
        }
    }
    __syncthreads();

    {   // h (fp16) + h8 (fp8): thread -> (node row = tid>>2, 32-feature chunk = tid&3)
        int rw = tid >> 2, ch = tid & 3;
        int gnode = bid * 64 + rw;
        if (gnode < NN) {
            const uint4* src = (const uint4*)&Cs[rw * WST + ch * 32];
            uint4 v[4] = { src[0], src[1], src[2], src[3] };
            uint4* dst = (uint4*)&h[((long)gnode << 7) + ch * 32];
            dst[0] = v[0]; dst[1] = v[1]; dst[2] = v[2]; dst[3] = v[3];

            const unsigned int* dw = (const unsigned int*)v;
            unsigned int res[8];
#pragma unroll
            for (int w = 0; w < 8; ++w) {
                unsigned int lo = dw[2 * w], hi = dw[2 * w + 1];
                float2 f0 = __half22float2(*(const __half2*)&lo);
                float2 f1 = __half22float2(*(const __half2*)&hi);
                unsigned int r = 0;
                r = __builtin_amdgcn_cvt_pk_fp8_f32(f0.x, f0.y, r, false);
                r = __builtin_amdgcn_cvt_pk_fp8_f32(f1.x, f1.y, r, true);
                res[w] = r;
            }
            uint4* d8 = (uint4*)&h8[((long)gnode << 7) + ch * 32];
            d8[0] = make_uint4(res[0], res[1], res[2], res[3]);
            d8[1] = make_uint4(res[4], res[5], res[6], res[7]);
        }
    }
    for (int p = tid; p < 512; p += 256) {   // al/ar: 64 nodes x 8 heads
        int nd = p >> 3, hh = p & 7;
        int gnode = bid * 64 + nd;
        if (gnode >= NN) continue;
        const _Float16* c = &Cs[nd * WST + hh * 16];
        float pL = 0.f, pR = 0.f;
#pragma unroll
        for (int f = 0; f < 16; ++f) {
            float hv = (float)c[f];
            pL = fmaf(hv, As[f], pL);
            pR = fmaf(hv, As[16 + f], pR);
        }
        al[gnode * 8 + hh] = pL;
        ar[gnode * 8 + hh] = pR;
    }
}

// ---------------------------------------------------------------------------
// csr v2: one 512-thread block per bucket; wave-per-segment. Wave w handles
// segments s = w, w+8, ...: lanes < cnt load the segment's edges (cap 64 =
// one lane each), LDS-atomic a slot in the 32 KB slab, then coalesced
// copy-out of cur + csr rows. ZERO global atomics.
// ---------------------------------------------------------------------------
__global__ __launch_bounds__(512) void csr_kernel(
    const unsigned* __restrict__ bkt, const unsigned* __restrict__ cnts,
    int* __restrict__ cur, unsigned short* __restrict__ csr)
{
    __shared__ unsigned short csl[256 * DSTRIDE];   // 32 KB
    __shared__ unsigned cnt256[256];
    __shared__ unsigned segcnt[NBKT];
    const int tid = threadIdx.x, bin = blockIdx.x;
    if (tid < 256) cnt256[tid] = 0;
    if (tid < NBKT) segcnt[tid] = cnts[tid * NBKT + bin];   // column gather
    __syncthreads();

    const int w = tid >> 6, lane = tid & 63;
    for (int s = w; s < NCHK; s += 8) {
        unsigned m = min(segcnt[s], (unsigned)BINCAP);
        if ((unsigned)lane < m) {
            unsigned p = bkt[(((unsigned)s * NBKT + bin) << 6) + lane];
            unsigned local = (p >> 16) & 255u;          // node within bucket
            unsigned slot = atomicAdd(&cnt256[local], 1u);
            if (slot < DSTRIDE) csl[(local << 6) + slot] = (unsigned short)(p & 0xFFFFu);
        }
    }
    __syncthreads();

    if (tid < 256) {
        const int gnode = bin * 256 + tid;
        if (gnode < NN) cur[gnode] = (int)cnt256[tid];  // true degree
    }
    const int nrows = min(256, NN - bin * 256);         // last bucket: 80 rows
    uint4* dst = (uint4*)(csr + ((size_t)bin << 14));
    const uint4* srcp = (const uint4*)csl;
    for (int i = tid; i < nrows * 8; i += 512) dst[i] = srcp[i];
    // tails beyond cnt hold garbage; gather reads only j < min(deg,DSTRIDE)
}

// ---------------------------------------------------------------------------
// gather v4 (unchanged, verified r7): single fully-masked 16-edge chunk loop.
// ---------------------------------------------------------------------------
#define H8LD(s) (*(const unsigned short*)(h8 + ((((unsigned)(s)) << 7) | (unsigned)c2)))
#define ARLD(s) (*(const float*)((const char*)ar + ((((unsigned)(s)) << 5) | arof)))
#define CSRLD(o) (*(const unsigned short*)((const char*)csr + (o)))

__global__ __launch_bounds__(256) void gather_kernel(
    const int* __restrict__ cur, const unsigned short* __restrict__ csr,
    const float* __restrict__ al, const float* __restrict__ ar,
    const __half* __restrict__ h, const unsigned char* __restrict__ h8,
    float* __restrict__ out)
{
    __shared__ __align__(16) float se[4][160];    // 8 heads x stride 20
    __shared__ __align__(16) int ssrc[4][16];
    const int wid = threadIdx.x >> 6;
    const int n = blockIdx.x * 4 + wid;
    if (n >= NN) return;
    const int lane = threadIdx.x & 63;
    const int c2 = lane << 1;
    const int hh = lane >> 3;
    const int el = lane & 7;
    const int deg = cur[n];                 // true degree (skip term)
    const int degc = min(deg, DSTRIDE);     // iterated edges
    const unsigned cbase = ((unsigned)n) << 7;     // byte offset of node's csr row
    const unsigned arof = ((unsigned)hh) << 2;     // byte offset of head within ar row
    const float aLt = al[n * 8 + hh];
    float* serow = &se[wid][hh * 20];

    floatx2 acc2 = {0.f, 0.f};
    floatx4 den4 = {0.f, 0.f, 0.f, 0.f};
    for (int j = 0; j < degc; j += 16) {
        const bool va = (j + el) < degc;
        const bool vb = (j + 8 + el) < degc;
        const unsigned co = cbase + (((unsigned)(j + el)) << 1);
        int ms0 = va ? (int)CSRLD(co) : 0;          // masked index: row 0 = real, finite data
        int ms1 = vb ? (int)CSRLD(co + 16u) : 0;
        float v0 = aLt + ARLD(ms0);
        float v1 = aLt + ARLD(ms1);
        v0 = v0 > 0.0f ? v0 : SLOPE * v0;
        v1 = v1 > 0.0f ? v1 : SLOPE * v1;
        float me0 = va ? __expf(fminf(v0, 60.0f)) : 0.0f;
        float me1 = vb ? __expf(fminf(v1, 60.0f)) : 0.0f;
        serow[el] = me0;
        serow[8 + el] = me1;
        if (hh == 0) { ssrc[wid][el] = ms0; ssrc[wid][8 + el] = ms1; }
        // per-wave LDS reuse: DS ops are in-order within a wave; fence stops
        // compiler reordering. NO __syncthreads (waves have divergent trips).
        __asm__ __volatile__("s_waitcnt lgkmcnt(0)" ::: "memory");
        floatx4 ea = *(const floatx4*)&serow[0];
        floatx4 eb = *(const floatx4*)&serow[4];
        floatx4 ec = *(const floatx4*)&serow[8];
        floatx4 ed = *(const floatx4*)&serow[12];
        intx4 sa = *(const intx4*)&ssrc[wid][0];
        intx4 sb = *(const intx4*)&ssrc[wid][4];
        intx4 sc = *(const intx4*)&ssrc[wid][8];
        intx4 sd = *(const intx4*)&ssrc[wid][12];
        // 16 independent 2B loads, issued back-to-back (MLP); each is a
        // wave-coalesced 128B row read (uniform row, lane*2 offset)
        unsigned short u0  = H8LD(sa[0]);
        unsigned short u1  = H8LD(sa[1]);
        unsigned short u2  = H8LD(sa[2]);
        unsigned short u3  = H8LD(sa[3]);
        unsigned short u4  = H8LD(sb[0]);
        unsigned short u5  = H8LD(sb[1]);
        unsigned short u6  = H8LD(sb[2]);
        unsigned short u7  = H8LD(sb[3]);
        unsigned short u8  = H8LD(sc[0]);
        unsigned short u9  = H8LD(sc[1]);
        unsigned short u10 = H8LD(sc[2]);
        unsigned short u11 = H8LD(sc[3]);
        unsigned short u12 = H8LD(sd[0]);
        unsigned short u13 = H8LD(sd[1]);
        unsigned short u14 = H8LD(sd[2]);
        unsigned short u15 = H8LD(sd[3]);
        den4 += ea; den4 += eb; den4 += ec; den4 += ed;
        floatx2 g;
        g = __builtin_amdgcn_cvt_pk_f32_fp8(u0,  false); acc2 += g * ea[0];
        g = __builtin_amdgcn_cvt_pk_f32_fp8(u1,  false); acc2 += g * ea[1];
        g = __builtin_amdgcn_cvt_pk_f32_fp8(u2,  false); acc2 += g * ea[2];
        g = __builtin_amdgcn_cvt_pk_f32_fp8(u3,  false); acc2 += g * ea[3];
        g = __builtin_amdgcn_cvt_pk_f32_fp8(u4,  false); acc2 += g * eb[0];
        g = __builtin_amdgcn_cvt_pk_f32_fp8(u5,  false); acc2 += g * eb[1];
        g = __builtin_amdgcn_cvt_pk_f32_fp8(u6,  false); acc2 += g * eb[2];
        g = __builtin_amdgcn_cvt_pk_f32_fp8(u7,  false); acc2 += g * eb[3];
        g = __builtin_amdgcn_cvt_pk_f32_fp8(u8,  false); acc2 += g * ec[0];
        g = __builtin_amdgcn_cvt_pk_f32_fp8(u9,  false); acc2 += g * ec[1];
        g = __builtin_amdgcn_cvt_pk_f32_fp8(u10, false); acc2 += g * ec[2];
        g = __builtin_amdgcn_cvt_pk_f32_fp8(u11, false); acc2 += g * ec[3];
        g = __builtin_amdgcn_cvt_pk_f32_fp8(u12, false); acc2 += g * ed[0];
        g = __builtin_amdgcn_cvt_pk_f32_fp8(u13, false); acc2 += g * ed[1];
        g = __builtin_amdgcn_cvt_pk_f32_fp8(u14, false); acc2 += g * ed[2];
        g = __builtin_amdgcn_cvt_pk_f32_fp8(u15, false); acc2 += g * ed[3];
    }

    unsigned hv = __builtin_nontemporal_load(
        (const unsigned*)((const char*)h + (((size_t)n) << 8) + ((unsigned)c2 << 1)));
    float2 hs = __half22float2(*(const __half2*)&hv);
    float den = (den4[0] + den4[1]) + (den4[2] + den4[3]);
    float degf = (float)deg;
    float inv = (den > 0.0f) ? 1.0f / den : 0.0f;
    float o0 = fmaf(degf, hs.x, acc2[0] * inv);
    float o1 = fmaf(degf, hs.y, acc2[1] * inv);
    o0 = o0 > 0.0f ? o0 : __expf(o0) - 1.0f;   // ELU; exp(x)-1 accurate enough for x<0
    o1 = o1 > 0.0f ? o1 : __expf(o1) - 1.0f;
    floatx2 res = {o0, o1};    // ext_vector_type: valid operand for nontemporal builtin
    __builtin_nontemporal_store(res,
        (floatx2*)((char*)out + (((size_t)n) << 9) + ((unsigned)c2 << 2)));
}

extern "C" void kernel_launch(void* const* d_in, const int* in_sizes, int n_in,
                              void* d_out, int out_size, void* d_ws, size_t ws_size,
                              hipStream_t stream) {
    const float* X = (const float*)d_in[0];
    const int* ei  = (const int*)d_in[1];
    const float* W = (const float*)d_in[2];
    const float* B = (const float*)d_in[3];
    const float* A = (const float*)d_in[4];
    float* ws  = (float*)d_ws;
    __half* h  = (__half*)(ws + OFF_H);
    unsigned char* h8 = (unsigned char*)(ws + OFF_H8);
    float* al  = ws + OFF_AL;
    float* ar  = ws + OFF_AR;
    int* cur   = (int*)ws + OFF_CUR;
    unsigned short* csr = (unsigned short*)(ws + OFF_CSR);
    unsigned* bkt  = (unsigned*)(ws + OFF_BKT);
    unsigned* cnts = (unsigned*)(ws + OFF_CNTS);
    float* out = (float*)d_out;

    project_bin_kernel<<<NTILES + NCHK, 256, 0, stream>>>(X, W, B, A, ei, h, h8, al, ar, bkt, cnts);
    csr_kernel<<<NBKT, 512, 0, stream>>>(bkt, cnts, cur, csr);
    gather_kernel<<<(NN + 3) / 4, 256, 0, stream>>>(cur, csr, al, ar, h, h8, out);
}

// Round 10
// 139.551 us; speedup vs baseline: 1.3559x; 1.0107x over previous
//
#include <hip/hip_runtime.h>
#include <hip/hip_fp16.h>
#include <cmath>

#define NN 50000
#define NE 800000
#define SLOPE 0.2f
#define NTILES 782           // ceil(50000/64)
#define DSTRIDE 64           // fixed CSR slots per node (max expected degree ~36)

#define NBKT 196             // buckets of 256 target nodes (49999>>8 == 195)
#define NCHK 196             // bin chunks of 4096 edges
#define BINCAP 64            // per-(chunk,bucket) capacity; mean 21, P(overflow)~1e-8

// workspace layout (4-byte units) — total ~39 MB
#define OFF_H    0           // __half h[NN*128]:    3,200,000 dwords
#define OFF_H8   3200000     // fp8 h8[NN*128]:      1,600,000 dwords
#define OFF_AL   4800000     // float al[NN*8]:        400,000
#define OFF_AR   5200000     // float ar[NN*8]:        400,000
#define OFF_CUR  5600000     // int cur[NN]:            50,000 (written by csr_kernel)
#define OFF_CSR  5650000     // ushort csr[NN*64]:   1,600,000 dwords
#define OFF_BKT  7250000     // u32 bkt[196*196*64]: 2,458,624 dwords
#define OFF_CNTS 9708624     // u32 cnts[196*196]:      38,416 dwords

using half8   = __attribute__((ext_vector_type(8))) _Float16;
using floatx4 = __attribute__((ext_vector_type(4))) float;
using floatx2 = __attribute__((ext_vector_type(2))) float;
using intx4   = __attribute__((ext_vector_type(4))) int;

#define WST 136

// ---------------------------------------------------------------------------
// fused project+bin (verified r9): blocks [0,NTILES) = MFMA projection;
// blocks [NTILES,+NCHK) bin 4096 edges into deterministic (chunk,bucket)
// regions — no global atomics, no scan. (r9 lesson: bin blocks tail behind
// project's occupancy, so this only saves a launch — kept for that.)
// ---------------------------------------------------------------------------
__global__ __launch_bounds__(256) void project_bin_kernel(
    const float* __restrict__ X,    // [NN,128]
    const float* __restrict__ W,    // [128,128] row-major W[o][k]
    const float* __restrict__ Bv,   // [128]
    const float* __restrict__ Av,   // [32]
    const int* __restrict__ ei,     // [2,NE]
    __half* __restrict__ h, unsigned char* __restrict__ h8,
    float* __restrict__ al, float* __restrict__ ar,
    unsigned* __restrict__ bkt, unsigned* __restrict__ cnts)
{
    __shared__ _Float16 Wh[128 * WST];   // 34.8 KB
    __shared__ _Float16 Cs[64 * WST];    // 17.4 KB
    __shared__ float As[32];
    __shared__ unsigned bincnt[NBKT];    // bin role only
    const int tid = threadIdx.x;
    const int bid = blockIdx.x;

    if (bid >= NTILES) {   // ---- bin role ----
        const int c = bid - NTILES;      // chunk index
        if (tid < NBKT) bincnt[tid] = 0;
        __syncthreads();
#pragma unroll
        for (int it = 0; it < 4; ++it) {
            const int e0 = c * 4096 + tid * 4 + it * 1024;
            if (e0 < NE) {   // NE%4==0 && e0%4==0 -> whole int4 group valid
                intx4 tg = *(const intx4*)(ei + NE + e0);
                intx4 sr = *(const intx4*)(ei + e0);
#pragma unroll
                for (int k = 0; k < 4; ++k) {
                    unsigned p = ((unsigned)tg[k] << 16) | (unsigned)sr[k];
                    unsigned b = p >> 24;                       // tgt>>8
                    unsigned slot = atomicAdd(&bincnt[b], 1u);  // LDS only
                    if (slot < BINCAP)
                        bkt[(((unsigned)c * NBKT + b) << 6) + slot] = p;
                }
            }
        }
        __syncthreads();
        if (tid < NBKT) cnts[c * NBKT + tid] = bincnt[tid];     // coalesced row
        return;
    }

    // ---- project role ----
    for (int i = tid; i < 128 * 128; i += 256) {
        int o = i >> 7, k = i & 127;
        Wh[o * WST + k] = (_Float16)W[i];
    }
    if (tid < 32) As[tid] = Av[tid];
    __syncthreads();

    const int wave = tid >> 6;
    const int lane = tid & 63;
    const int q = lane >> 4;
    const int n = lane & 15;
    const int gn = bid * 64 + wave * 16 + n;
    const bool valid = gn < NN;
    const float* xrow = X + ((long)gn << 7);

    half8 afrag[4];
#pragma unroll
    for (int kc = 0; kc < 4; ++kc) {
        float4 x0 = make_float4(0.f, 0.f, 0.f, 0.f), x1 = x0;
        if (valid) {
            x0 = *(const float4*)(xrow + kc * 32 + q * 8);
            x1 = *(const float4*)(xrow + kc * 32 + q * 8 + 4);
        }
        half8 a;
        a[0] = (_Float16)x0.x; a[1] = (_Float16)x0.y;
        a[2] = (_Float16)x0.z; a[3] = (_Float16)x0.w;
        a[4] = (_Float16)x1.x; a[5] = (_Float16)x1.y;
        a[6] = (_Float16)x1.z; a[7] = (_Float16)x1.w;
        afrag[kc] = a;
    }

    floatx4 acc[8];
#pragma unroll
    for (int nt = 0; nt < 8; ++nt) {
        float b = Bv[nt * 16 + n];
        acc[nt][0] = b; acc[nt][1] = b; acc[nt][2] = b; acc[nt][3] = b;
    }
#pragma unroll
    for (int nt = 0; nt < 8; ++nt) {
        const _Float16* wrow = &Wh[(nt * 16 + n) * WST];
#pragma unroll
        for (int kc = 0; kc < 4; ++kc) {
            half8 bfrag = *(const half8*)(wrow + kc * 32 + q * 8);
            acc[nt] = __builtin_amdgcn_mfma_f32_16x16x32_f16(afrag[kc], bfrag, acc[nt], 0, 0, 0);
        }
    }

    // C/D layout: lane holds C[m=q*4+r][n] -> Cs[node][feature]
    _Float16* cw = &Cs[(wave * 16) * WST];
#pragma unroll
    for (int nt = 0; nt < 8; ++nt) {
#pragma unroll
        for (int r = 0; r < 4; ++r) {
            cw[(q * 4 + r) * WST + nt * 16 + n] = (_Float16)acc[nt][r];
        }
    }
    __syncthreads();

    {   // h (fp16) + h8 (fp8): thread -> (node row = tid>>2, 32-feature chunk = tid&3)
        int rw = tid >> 2, ch = tid & 3;
        int gnode = bid * 64 + rw;
        if (gnode < NN) {
            const uint4* src = (const uint4*)&Cs[rw * WST + ch * 32];
            uint4 v[4] = { src[0], src[1], src[2], src[3] };
            uint4* dst = (uint4*)&h[((long)gnode << 7) + ch * 32];
            dst[0] = v[0]; dst[1] = v[1]; dst[2] = v[2]; dst[3] = v[3];

            const unsigned int* dw = (const unsigned int*)v;
            unsigned int res[8];
#pragma unroll
            for (int w = 0; w < 8; ++w) {
                unsigned int lo = dw[2 * w], hi = dw[2 * w + 1];
                float2 f0 = __half22float2(*(const __half2*)&lo);
                float2 f1 = __half22float2(*(const __half2*)&hi);
                unsigned int r = 0;
                r = __builtin_amdgcn_cvt_pk_fp8_f32(f0.x, f0.y, r, false);
                r = __builtin_amdgcn_cvt_pk_fp8_f32(f1.x, f1.y, r, true);
                res[w] = r;
            }
            uint4* d8 = (uint4*)&h8[((long)gnode << 7) + ch * 32];
            d8[0] = make_uint4(res[0], res[1], res[2], res[3]);
            d8[1] = make_uint4(res[4], res[5], res[6], res[7]);
        }
    }
    for (int p = tid; p < 512; p += 256) {   // al/ar: 64 nodes x 8 heads
        int nd = p >> 3, hh = p & 7;
        int gnode = bid * 64 + nd;
        if (gnode >= NN) continue;
        const _Float16* c = &Cs[nd * WST + hh * 16];
        float pL = 0.f, pR = 0.f;
#pragma unroll
        for (int f = 0; f < 16; ++f) {
            float hv = (float)c[f];
            pL = fmaf(hv, As[f], pL);
            pR = fmaf(hv, As[16 + f], pR);
        }
        al[gnode * 8 + hh] = pL;
        ar[gnode * 8 + hh] = pR;
    }
}

// ---------------------------------------------------------------------------
// csr v2 (verified r9): one 512-thread block per bucket; wave-per-segment,
// LDS atomics only, coalesced copy-out. ZERO global atomics.
// ---------------------------------------------------------------------------
__global__ __launch_bounds__(512) void csr_kernel(
    const unsigned* __restrict__ bkt, const unsigned* __restrict__ cnts,
    int* __restrict__ cur, unsigned short* __restrict__ csr)
{
    __shared__ unsigned short csl[256 * DSTRIDE];   // 32 KB
    __shared__ unsigned cnt256[256];
    __shared__ unsigned segcnt[NBKT];
    const int tid = threadIdx.x, bin = blockIdx.x;
    if (tid < 256) cnt256[tid] = 0;
    if (tid < NBKT) segcnt[tid] = cnts[tid * NBKT + bin];   // column gather
    __syncthreads();

    const int w = tid >> 6, lane = tid & 63;
    for (int s = w; s < NCHK; s += 8) {
        unsigned m = min(segcnt[s], (unsigned)BINCAP);
        if ((unsigned)lane < m) {
            unsigned p = bkt[(((unsigned)s * NBKT + bin) << 6) + lane];
            unsigned local = (p >> 16) & 255u;          // node within bucket
            unsigned slot = atomicAdd(&cnt256[local], 1u);
            if (slot < DSTRIDE) csl[(local << 6) + slot] = (unsigned short)(p & 0xFFFFu);
        }
    }
    __syncthreads();

    if (tid < 256) {
        const int gnode = bin * 256 + tid;
        if (gnode < NN) cur[gnode] = (int)cnt256[tid];  // true degree
    }
    const int nrows = min(256, NN - bin * 256);         // last bucket: 80 rows
    uint4* dst = (uint4*)(csr + ((size_t)bin << 14));
    const uint4* srcp = (const uint4*)csl;
    for (int i = tid; i < nrows * 8; i += 512) dst[i] = srcp[i];
    // tails beyond cnt hold garbage; gather reads only j < min(deg,DSTRIDE)
}

// ---------------------------------------------------------------------------
// gather v5: NO LDS, NO per-chunk exchange. Lane (hh,el) owns edges {el,el+8}
// of each 16-edge chunk AND all 16 features of head hh: one dwordx4 load of
// h8[src][hh*16..+16) delivers the whole head-slice for its edge (the wave's
// 2 dwordx4 cover the same 2KB/32 lines the old 16 ushort loads did — 8x
// fewer VMEM insts), and the weight me is already lane-local. The old per-
// chunk {LDS write, lgkmcnt(0) stop, LDS read, ssrc broadcast} disappears.
// One reduce-scatter per NODE (14 shfl_xor + 7 pk_add over the 8-lane group)
// leaves lane el holding pair q=el = features [16hh+2el,+2) = exactly its c2
// output slot (final pair index = (el&4)+(el&2)+(el&1) = el).
// ---------------------------------------------------------------------------
#define ARLD(s) (*(const float*)((const char*)ar + ((((unsigned)(s)) << 5) | arof)))
#define CSRLD(o) (*(const unsigned short*)((const char*)csr + (o)))
#define CVTLO(w) __builtin_amdgcn_cvt_pk_f32_fp8((unsigned short)(w), false)
#define CVTHI(w) __builtin_amdgcn_cvt_pk_f32_fp8((unsigned short)((w) >> 16), false)

__global__ __launch_bounds__(256) void gather_kernel(
    const int* __restrict__ cur, const unsigned short* __restrict__ csr,
    const float* __restrict__ al, const float* __restrict__ ar,
    const __half* __restrict__ h, const unsigned char* __restrict__ h8,
    float* __restrict__ out)
{
    const int wid = threadIdx.x >> 6;
    const int n = blockIdx.x * 4 + wid;
    if (n >= NN) return;
    const int lane = threadIdx.x & 63;
    const int c2 = lane << 1;
    const int hh = lane >> 3;
    const int el = lane & 7;
    const int deg = cur[n];                 // true degree (skip term)
    const int degc = min(deg, DSTRIDE);     // iterated edges
    const unsigned cbase = ((unsigned)n) << 7;     // byte offset of node's csr row
    const unsigned arof = ((unsigned)hh) << 2;     // byte offset of head within ar row
    const unsigned hof = ((unsigned)hh) << 4;      // byte offset of head slice in h8 row
    const float aLt = al[n * 8 + hh];

    // 8 feature-pair accumulators of head hh (16 floats) + denominator
    floatx2 a0 = {0.f,0.f}, a1 = a0, a2 = a0, a3 = a0, a4 = a0, a5 = a0, a6 = a0, a7 = a0;
    float den = 0.f;

    for (int j = 0; j < degc; j += 16) {
        const bool va = (j + el) < degc;
        const bool vb = (j + 8 + el) < degc;
        const unsigned co = cbase + (((unsigned)(j + el)) << 1);
        int ms0 = va ? (int)CSRLD(co) : 0;          // masked index: row 0 = real, finite data
        int ms1 = vb ? (int)CSRLD(co + 16u) : 0;
        float v0 = aLt + ARLD(ms0);
        float v1 = aLt + ARLD(ms1);
        v0 = v0 > 0.0f ? v0 : SLOPE * v0;
        v1 = v1 > 0.0f ? v1 : SLOPE * v1;
        float me0 = va ? __expf(fminf(v0, 60.0f)) : 0.0f;
        float me1 = vb ? __expf(fminf(v1, 60.0f)) : 0.0f;
        // full head-slice loads: 16B = features [16hh,16hh+16) of each edge's row
        uint4 A = *(const uint4*)(h8 + ((((unsigned)ms0) << 7) | hof));
        uint4 B = *(const uint4*)(h8 + ((((unsigned)ms1) << 7) | hof));
        den += me0 + me1;
        a0 += CVTLO(A.x) * me0; a1 += CVTHI(A.x) * me0;
        a2 += CVTLO(A.y) * me0; a3 += CVTHI(A.y) * me0;
        a4 += CVTLO(A.z) * me0; a5 += CVTHI(A.z) * me0;
        a6 += CVTLO(A.w) * me0; a7 += CVTHI(A.w) * me0;
        a0 += CVTLO(B.x) * me1; a1 += CVTHI(B.x) * me1;
        a2 += CVTLO(B.y) * me1; a3 += CVTHI(B.y) * me1;
        a4 += CVTLO(B.z) * me1; a5 += CVTHI(B.z) * me1;
        a6 += CVTLO(B.w) * me1; a7 += CVTHI(B.w) * me1;
    }

    // reduce-scatter over the 8-lane head group: lane el ends with pair q=el.
    // level mask=4: owned pairs have (q&4)==(el&4); exchange my not-owned
    // (= partner's owned index) and add into my owned.
    {
        floatx2 v0_ = (el & 4) ? a0 : a4;
        floatx2 v1_ = (el & 4) ? a1 : a5;
        floatx2 v2_ = (el & 4) ? a2 : a6;
        floatx2 v3_ = (el & 4) ? a3 : a7;
        floatx2 o0 = (el & 4) ? a4 : a0;
        floatx2 o1 = (el & 4) ? a5 : a1;
        floatx2 o2 = (el & 4) ? a6 : a2;
        floatx2 o3 = (el & 4) ? a7 : a3;
        o0[0] += __shfl_xor(v0_[0], 4); o0[1] += __shfl_xor(v0_[1], 4);
        o1[0] += __shfl_xor(v1_[0], 4); o1[1] += __shfl_xor(v1_[1], 4);
        o2[0] += __shfl_xor(v2_[0], 4); o2[1] += __shfl_xor(v2_[1], 4);
        o3[0] += __shfl_xor(v3_[0], 4); o3[1] += __shfl_xor(v3_[1], 4);
        // level mask=2
        floatx2 w0 = (el & 2) ? o0 : o2;
        floatx2 w1 = (el & 2) ? o1 : o3;
        floatx2 p0 = (el & 2) ? o2 : o0;
        floatx2 p1 = (el & 2) ? o3 : o1;
        p0[0] += __shfl_xor(w0[0], 2); p0[1] += __shfl_xor(w0[1], 2);
        p1[0] += __shfl_xor(w1[0], 2); p1[1] += __shfl_xor(w1[1], 2);
        // level mask=1
        floatx2 z = (el & 1) ? p0 : p1;
        floatx2 fin = (el & 1) ? p1 : p0;
        fin[0] += __shfl_xor(z[0], 1); fin[1] += __shfl_xor(z[1], 1);
        a0 = fin;   // a0 now = group-summed accumulator for pair q=el (features c2,c2+1)
    }
    den += __shfl_xor(den, 1);
    den += __shfl_xor(den, 2);
    den += __shfl_xor(den, 4);

    unsigned hv = __builtin_nontemporal_load(
        (const unsigned*)((const char*)h + (((size_t)n) << 8) + ((unsigned)c2 << 1)));
    float2 hs = __half22float2(*(const __half2*)&hv);
    float degf = (float)deg;
    float inv = (den > 0.0f) ? 1.0f / den : 0.0f;
    float o0 = fmaf(degf, hs.x, a0[0] * inv);
    float o1 = fmaf(degf, hs.y, a0[1] * inv);
    o0 = o0 > 0.0f ? o0 : __expf(o0) - 1.0f;   // ELU; exp(x)-1 accurate enough for x<0
    o1 = o1 > 0.0f ? o1 : __expf(o1) - 1.0f;
    floatx2 res = {o0, o1};
    __builtin_nontemporal_store(res,
        (floatx2*)((char*)out + (((size_t)n) << 9) + ((unsigned)c2 << 2)));
}

extern "C" void kernel_launch(void* const* d_in, const int* in_sizes, int n_in,
                              void* d_out, int out_size, void* d_ws, size_t ws_size,
                              hipStream_t stream) {
    const float* X = (const float*)d_in[0];
    const int* ei  = (const int*)d_in[1];
    const float* W = (const float*)d_in[2];
    const float* B = (const float*)d_in[3];
    const float* A = (const float*)d_in[4];
    float* ws  = (float*)d_ws;
    __half* h  = (__half*)(ws + OFF_H);
    unsigned char* h8 = (unsigned char*)(ws + OFF_H8);
    float* al  = ws + OFF_AL;
    float* ar  = ws + OFF_AR;
    int* cur   = (int*)ws + OFF_CUR;
    unsigned short* csr = (unsigned short*)(ws + OFF_CSR);
    unsigned* bkt  = (unsigned*)(ws + OFF_BKT);
    unsigned* cnts = (unsigned*)(ws + OFF_CNTS);
    float* out = (float*)d_out;

    project_bin_kernel<<<NTILES + NCHK, 256, 0, stream>>>(X, W, B, A, ei, h, h8, al, ar, bkt, cnts);
    csr_kernel<<<NBKT, 512, 0, stream>>>(bkt, cnts, cur, csr);
    gather_kernel<<<(NN + 3) / 4, 256, 0, stream>>>(cur, csr, al, ar, h, h8, out);
}